// Round 12
// baseline (1542.982 us; speedup 1.0000x reference)
//
#include <hip/hip_runtime.h>
#include <math.h>

#define CDIM 256
#define LSEQ 4096
#define NBH 16
#define NPTS 65536
#define KC 256

__device__ __forceinline__ float fadd(float a, float b){ return __fadd_rn(a,b); }
__device__ __forceinline__ float fmul(float a, float b){ return __fmul_rn(a,b); }
__device__ __forceinline__ float fsub(float a, float b){ return __fsub_rn(a,b); }

// async global->LDS, width 4: per-lane global src, wave-uniform LDS base,
// lane i lands at base + i*4 (guide §5 / m03)
__device__ __forceinline__ void gld_lds4(const float* g, float* l){
    __builtin_amdgcn_global_load_lds(
        (const __attribute__((address_space(1))) unsigned int*)g,
        (__attribute__((address_space(3))) unsigned int*)l, 4, 0, 0);
}

// numpy contiguous n=32 float32 sum, AVX-512 npyv path (verified R5)
__device__ __forceinline__ float sum32_np(const float* e){
    float l[16];
    #pragma unroll
    for (int j = 0; j < 16; j++) l[j] = fadd(e[j], e[j + 16]);
    float t3[8];
    #pragma unroll
    for (int j = 0; j < 8; j++) t3[j] = fadd(l[j], l[j + 8]);
    float t6[4];
    #pragma unroll
    for (int j = 0; j < 4; j++) t6[j] = fadd(t3[j], t3[j + 4]);
    return fadd(fadd(t6[0], t6[2]), fadd(t6[1], t6[3]));
}

// ---------- both LayerNorms, LDS-cached (numpy exact per position) --
__global__ __launch_bounds__(64) void ln2_np(
        const float* __restrict__ x0, const float* __restrict__ g0,
        const float* __restrict__ bt0, float* __restrict__ y0,
        const float* __restrict__ x1, const float* __restrict__ g1,
        const float* __restrict__ bt1, float* __restrict__ y1) {
    __shared__ float xl[256 * 64];
    int tid = threadIdx.x;
    int gid = blockIdx.x * 64 + tid;
    int which = gid >> 13;
    int r = gid & 8191;
    int b = r >> 12, l = r & 4095;
    const float* x  = which ? x1 : x0;
    const float* g  = which ? g1 : g0;
    const float* bt = which ? bt1 : bt0;
    float* y        = which ? y1 : y0;
    const float* xb = x + (size_t)b * CDIM * LSEQ + l;
    #pragma unroll 8
    for (int c = 0; c < 256; c++)
        gld_lds4(xb + (size_t)c * LSEQ, xl + c * 64);
    __syncthreads();
    float s = 0.f;
    #pragma unroll 8
    for (int c = 0; c < 256; c++) s = fadd(s, xl[c * 64 + tid]);
    float mean = __fdiv_rn(s, 256.f);
    float s2 = 0.f;
    #pragma unroll 8
    for (int c = 0; c < 256; c++) {
        float d = fsub(xl[c * 64 + tid], mean);
        s2 = fadd(s2, fmul(d, d));
    }
    float var = __fdiv_rn(s2, 256.f);
    float den = fadd(__fsqrt_rn(var), 1e-6f);
    float* yb = y + (size_t)b * CDIM * LSEQ + l;
    #pragma unroll 4
    for (int c = 0; c < 256; c++) {
        float d = fsub(xl[c * 64 + tid], mean);
        yb[(size_t)c * LSEQ] = fadd(__fdiv_rn(fmul(g[c], d), den), bt[c]);
    }
}

// ---------- fused conv (kv + q), COT=16, NL=2, no LDS (R6 = 58.5us) -
__global__ __launch_bounds__(256) void conv_all16(
        const float* __restrict__ Wkv, const float* __restrict__ Xkv,
        float* __restrict__ Ykv,
        const float* __restrict__ Wq, const float* __restrict__ Xq,
        float* __restrict__ Yq) {
    int tid = threadIdx.x;
    int l0 = blockIdx.x * 512 + tid * 2;
    bool qpath = blockIdx.y >= 32;
    int yb = qpath ? (blockIdx.y - 32) : blockIdx.y;
    int o0 = yb * 16;
    int b = blockIdx.z;
    const float4* w4 = (const float4*)((qpath ? Wq : Wkv) + (size_t)o0 * CDIM);
    const float* X = qpath ? Xq : Xkv;
    const float* xb = X + (size_t)b * CDIM * LSEQ;
    float acc[16][2];
    #pragma unroll
    for (int oo = 0; oo < 16; oo++) { acc[oo][0] = 0.f; acc[oo][1] = 0.f; }
    bool sop = qpath || (blockIdx.y < 16);
    if (sop) {
        for (int c = 0; c < 256; c += 4) {
            float2 x0q = *(const float2*)(xb + (size_t)(c + 0) * LSEQ + l0);
            float2 x1q = *(const float2*)(xb + (size_t)(c + 1) * LSEQ + l0);
            float2 x2q = *(const float2*)(xb + (size_t)(c + 2) * LSEQ + l0);
            float2 x3q = *(const float2*)(xb + (size_t)(c + 3) * LSEQ + l0);
            #pragma unroll
            for (int oo = 0; oo < 16; oo++) {
                float4 w = w4[(oo * 256 + c) >> 2];
                acc[oo][0] = fadd(acc[oo][0], fmul(w.x, x0q.x));
                acc[oo][0] = fadd(acc[oo][0], fmul(w.y, x1q.x));
                acc[oo][0] = fadd(acc[oo][0], fmul(w.z, x2q.x));
                acc[oo][0] = fadd(acc[oo][0], fmul(w.w, x3q.x));
                acc[oo][1] = fadd(acc[oo][1], fmul(w.x, x0q.y));
                acc[oo][1] = fadd(acc[oo][1], fmul(w.y, x1q.y));
                acc[oo][1] = fadd(acc[oo][1], fmul(w.z, x2q.y));
                acc[oo][1] = fadd(acc[oo][1], fmul(w.w, x3q.y));
            }
        }
    } else {
        for (int c = 0; c < 256; c += 4) {
            float2 x0q = *(const float2*)(xb + (size_t)(c + 0) * LSEQ + l0);
            float2 x1q = *(const float2*)(xb + (size_t)(c + 1) * LSEQ + l0);
            float2 x2q = *(const float2*)(xb + (size_t)(c + 2) * LSEQ + l0);
            float2 x3q = *(const float2*)(xb + (size_t)(c + 3) * LSEQ + l0);
            #pragma unroll
            for (int oo = 0; oo < 16; oo++) {
                float4 w = w4[(oo * 256 + c) >> 2];
                acc[oo][0] = __builtin_fmaf(w.x, x0q.x, acc[oo][0]);
                acc[oo][0] = __builtin_fmaf(w.y, x1q.x, acc[oo][0]);
                acc[oo][0] = __builtin_fmaf(w.z, x2q.x, acc[oo][0]);
                acc[oo][0] = __builtin_fmaf(w.w, x3q.x, acc[oo][0]);
                acc[oo][1] = __builtin_fmaf(w.x, x0q.y, acc[oo][1]);
                acc[oo][1] = __builtin_fmaf(w.y, x1q.y, acc[oo][1]);
                acc[oo][1] = __builtin_fmaf(w.z, x2q.y, acc[oo][1]);
                acc[oo][1] = __builtin_fmaf(w.w, x3q.y, acc[oo][1]);
            }
        }
    }
    float* Y = qpath ? Yq : Ykv;
    int rows = qpath ? 256 : 512;
    #pragma unroll
    for (int oo = 0; oo < 16; oo++)
        *(float2*)(Y + ((size_t)b * rows + o0 + oo) * LSEQ + l0) =
            make_float2(acc[oo][0], acc[oo][1]);
}

// ---------- conv 256-row: COT=8, NL=4, LDS (exact R4 version) -------
template<bool EXACT>
__global__ __launch_bounds__(256) void conv_q8(const float* __restrict__ W,
        const float* __restrict__ X, float* __restrict__ Y) {
    __shared__ float ws[8 * 256];
    int tid = threadIdx.x;
    int l0 = blockIdx.x * 1024 + tid * 4;
    int o0 = blockIdx.y * 8;
    int b = blockIdx.z;
    {
        const float4* wb4 = (const float4*)(W + (size_t)o0 * CDIM);
        float4* ws4s = (float4*)ws;
        for (int i = tid; i < 8 * 64; i += 256) ws4s[i] = wb4[i];
    }
    __syncthreads();
    const float* xb = X + (size_t)b * CDIM * LSEQ;
    float acc[8][4];
    #pragma unroll
    for (int oo = 0; oo < 8; oo++)
        #pragma unroll
        for (int i = 0; i < 4; i++) acc[oo][i] = 0.f;
    const float4* ws4 = (const float4*)ws;
    for (int c = 0; c < 256; c += 4) {
        float4 x0q = *(const float4*)(xb + (size_t)(c + 0) * LSEQ + l0);
        float4 x1q = *(const float4*)(xb + (size_t)(c + 1) * LSEQ + l0);
        float4 x2q = *(const float4*)(xb + (size_t)(c + 2) * LSEQ + l0);
        float4 x3q = *(const float4*)(xb + (size_t)(c + 3) * LSEQ + l0);
        #pragma unroll
        for (int oo = 0; oo < 8; oo++) {
            float4 w = ws4[(oo * 256 + c) >> 2];
            if (EXACT) {
                acc[oo][0] = fadd(acc[oo][0], fmul(w.x, x0q.x));
                acc[oo][0] = fadd(acc[oo][0], fmul(w.y, x1q.x));
                acc[oo][0] = fadd(acc[oo][0], fmul(w.z, x2q.x));
                acc[oo][0] = fadd(acc[oo][0], fmul(w.w, x3q.x));
                acc[oo][1] = fadd(acc[oo][1], fmul(w.x, x0q.y));
                acc[oo][1] = fadd(acc[oo][1], fmul(w.y, x1q.y));
                acc[oo][1] = fadd(acc[oo][1], fmul(w.z, x2q.y));
                acc[oo][1] = fadd(acc[oo][1], fmul(w.w, x3q.y));
                acc[oo][2] = fadd(acc[oo][2], fmul(w.x, x0q.z));
                acc[oo][2] = fadd(acc[oo][2], fmul(w.y, x1q.z));
                acc[oo][2] = fadd(acc[oo][2], fmul(w.z, x2q.z));
                acc[oo][2] = fadd(acc[oo][2], fmul(w.w, x3q.z));
                acc[oo][3] = fadd(acc[oo][3], fmul(w.x, x0q.w));
                acc[oo][3] = fadd(acc[oo][3], fmul(w.y, x1q.w));
                acc[oo][3] = fadd(acc[oo][3], fmul(w.z, x2q.w));
                acc[oo][3] = fadd(acc[oo][3], fmul(w.w, x3q.w));
            } else {
                acc[oo][0] = __builtin_fmaf(w.x, x0q.x, acc[oo][0]);
                acc[oo][0] = __builtin_fmaf(w.y, x1q.x, acc[oo][0]);
                acc[oo][0] = __builtin_fmaf(w.z, x2q.x, acc[oo][0]);
                acc[oo][0] = __builtin_fmaf(w.w, x3q.x, acc[oo][0]);
                acc[oo][1] = __builtin_fmaf(w.x, x0q.y, acc[oo][1]);
                acc[oo][1] = __builtin_fmaf(w.y, x1q.y, acc[oo][1]);
                acc[oo][1] = __builtin_fmaf(w.z, x2q.y, acc[oo][1]);
                acc[oo][1] = __builtin_fmaf(w.w, x3q.y, acc[oo][1]);
                acc[oo][2] = __builtin_fmaf(w.x, x0q.z, acc[oo][2]);
                acc[oo][2] = __builtin_fmaf(w.y, x1q.z, acc[oo][2]);
                acc[oo][2] = __builtin_fmaf(w.z, x2q.z, acc[oo][2]);
                acc[oo][2] = __builtin_fmaf(w.w, x3q.z, acc[oo][2]);
                acc[oo][3] = __builtin_fmaf(w.x, x0q.w, acc[oo][3]);
                acc[oo][3] = __builtin_fmaf(w.y, x1q.w, acc[oo][3]);
                acc[oo][3] = __builtin_fmaf(w.z, x2q.w, acc[oo][3]);
                acc[oo][3] = __builtin_fmaf(w.w, x3q.w, acc[oo][3]);
            }
        }
    }
    #pragma unroll
    for (int oo = 0; oo < 8; oo++)
        *(float4*)(Y + ((size_t)b * 256 + o0 + oo) * LSEQ + l0) =
            make_float4(acc[oo][0], acc[oo][1], acc[oo][2], acc[oo][3]);
}

// ---------- fold x3 (k norm, v plain, q norm+xx+cent/cc) ------------
__device__ __forceinline__ void fold_body(const float* __restrict__ src,
        int srcRows, int row0, int donorm, float* __restrict__ dst,
        float* __restrict__ xxout, float* __restrict__ centout,
        float* __restrict__ ccout, int p) {
    int bh = p >> 12, l = p & 4095;
    int b = bh >> 3, h = bh & 7;
    const float* sp = src + ((size_t)b * srcRows + row0 + h * 32) * LSEQ + l;
    float x[32];
    #pragma unroll
    for (int t = 0; t < 32; t++) x[t] = sp[(size_t)t * LSEQ];
    float4* dp4 = (float4*)(dst + (size_t)p * 32);
    if (donorm) {
        float ss = 0.f;
        #pragma unroll
        for (int t = 0; t < 32; t++) ss = fadd(ss, fmul(x[t], x[t]));
        float n = __fsqrt_rn(ss);
        float den = fmaxf(n, 1e-12f);
        #pragma unroll
        for (int t = 0; t < 32; t++) x[t] = __fdiv_rn(x[t], den);
    }
    #pragma unroll
    for (int t = 0; t < 8; t++)
        dp4[t] = make_float4(x[4*t], x[4*t+1], x[4*t+2], x[4*t+3]);
    if (xxout) {
        float e[32];
        #pragma unroll
        for (int t = 0; t < 32; t++) e[t] = fmul(x[t], x[t]);
        float xv = sum32_np(e);
        xxout[p] = xv;
        if (centout && p < KC) {
            float4* cp4 = (float4*)(centout + (size_t)p * 32);
            #pragma unroll
            for (int t = 0; t < 8; t++)
                cp4[t] = make_float4(x[4*t], x[4*t+1], x[4*t+2], x[4*t+3]);
            ccout[p] = xv;
        }
    }
}

__global__ __launch_bounds__(256) void fold3_np(const float* __restrict__ kvbuf,
        const float* __restrict__ qbuf, float* __restrict__ k_t,
        float* __restrict__ v_t, float* __restrict__ q_t,
        float* __restrict__ xx, float* __restrict__ cent, float* __restrict__ cc) {
    int blk = blockIdx.x, tid = threadIdx.x;
    if (blk < 256) {
        fold_body(kvbuf, 512, 0, 1, k_t, nullptr, nullptr, nullptr, blk * 256 + tid);
    } else if (blk < 512) {
        fold_body(kvbuf, 512, 256, 0, v_t, nullptr, nullptr, nullptr, (blk - 256) * 256 + tid);
    } else {
        fold_body(qbuf, 256, 0, 1, q_t, xx, cent, cc, (blk - 512) * 256 + tid);
    }
}

// ---------- manual grid barrier: monotonic agent-scope atomic -------
// Plain-launch-safe (no cooperative API, works under graph capture).
// acq_rel RMW releases this block's writes; acquire spin-load
// invalidates stale L1/L2 before phase reads (cross-XCD safe).
// Deadlock-free by capacity: 256 blocks, LDS 38.9KB -> >=4 blk/CU
// capacity (1024 slots >> 256), so all blocks are always resident.
__device__ __forceinline__ void gbar(int* bar) {
    __syncthreads();
    if (threadIdx.x == 0) {
        int old = __hip_atomic_fetch_add(bar, 1, __ATOMIC_ACQ_REL,
                                         __HIP_MEMORY_SCOPE_AGENT);
        int want = (old / 256 + 1) * 256;
        while (__hip_atomic_load(bar, __ATOMIC_ACQUIRE,
                                 __HIP_MEMORY_SCOPE_AGENT) < want) {
            __builtin_amdgcn_s_sleep(8);
        }
    }
    __syncthreads();
}

// ---------- fused k-means: 10 iterations, 1 plain launch ------------
// Replaces 50 dispatches (10 x {assign_h, merge_asn, scan_chunks,
// scatter_v5, sumk_v4}). Phase bodies verbatim from R10; phase A is
// the single-pass 256-cluster assign (conflict-free pad-36 rows +
// interleaved j=4*jj+q; lex (d,j) min == half-split + prefer-half0
// merge == numpy first-occurrence argmin).
#define STILE 128
__global__ __launch_bounds__(256, 1) void kmeans_fused(
        const float* __restrict__ pts, const float* __restrict__ xx,
        float* __restrict__ cent, float* __restrict__ cc,
        int* __restrict__ asn, int* __restrict__ hist,
        int* __restrict__ chunkbase, int* __restrict__ totals,
        int* __restrict__ perm, int* bar, int iters) {
    __shared__ __align__(16) char sm[38912];
    int tid = threadIdx.x;
    int blk = blockIdx.x;

    for (int it = 0; it < iters; it++) {
        // ---- phase A: assign (block = chunk), conflict-free LDS ----
        {
            float* sc  = (float*)sm;            // 256 rows * 36 = 36864 B
            float* scc = (float*)(sm + 36864);  // 1024 B
            int*  bins = (int*) (sm + 37888);   // 1024 B
            const float4* c4 = (const float4*)cent;
            for (int i = tid; i < 2048; i += 256) {
                int row = i >> 3, t = i & 7;
                ((float4*)(sc + row * 36))[t] = c4[i];
            }
            scc[tid] = cc[tid];
            bins[tid] = 0;
            __syncthreads();
            int pg = tid >> 2, quarter = tid & 3;
            int pb = blk * 256 + pg * 4;
            float x[4][32];
            float xp[4];
            #pragma unroll
            for (int i = 0; i < 4; i++) {
                const float4* pp = (const float4*)(pts + (size_t)(pb + i) * 32);
                #pragma unroll
                for (int t = 0; t < 8; t++) {
                    float4 f = pp[t];
                    x[i][4*t] = f.x; x[i][4*t+1] = f.y; x[i][4*t+2] = f.z; x[i][4*t+3] = f.w;
                }
                xp[i] = xx[pb + i];
            }
            float bd[4] = {3.4e38f, 3.4e38f, 3.4e38f, 3.4e38f};
            int bj[4] = {0x7fffffff, 0x7fffffff, 0x7fffffff, 0x7fffffff};
            for (int jj = 0; jj < 64; jj++) {
                int j = (jj << 2) | quarter;
                const float4* cj = (const float4*)(sc + j * 36);
                float w[32];
                #pragma unroll
                for (int t = 0; t < 8; t++) {
                    float4 f = cj[t];
                    w[4*t] = f.x; w[4*t+1] = f.y; w[4*t+2] = f.z; w[4*t+3] = f.w;
                }
                float sj = scc[j];
                #pragma unroll
                for (int i = 0; i < 4; i++) {
                    float g = 0.f;
                    #pragma unroll
                    for (int t = 0; t < 32; t++) g = __builtin_fmaf(x[i][t], w[t], g);
                    float d = fadd(fsub(xp[i], fmul(2.f, g)), sj);
                    if (d < bd[i]) { bd[i] = d; bj[i] = j; }
                }
            }
            // lexicographic (d, j) combine across the 4 quarters
            #pragma unroll
            for (int i = 0; i < 4; i++) {
                float ob; int oj;
                ob = __shfl_xor(bd[i], 1); oj = __shfl_xor(bj[i], 1);
                if (ob < bd[i] || (ob == bd[i] && oj < bj[i])) { bd[i] = ob; bj[i] = oj; }
                ob = __shfl_xor(bd[i], 2); oj = __shfl_xor(bj[i], 2);
                if (ob < bd[i] || (ob == bd[i] && oj < bj[i])) { bd[i] = ob; bj[i] = oj; }
            }
            if (quarter == 0) {
                #pragma unroll
                for (int i = 0; i < 4; i++) {
                    asn[pb + i] = bj[i];
                    atomicAdd(&bins[bj[i]], 1);
                }
            }
            __syncthreads();
            hist[blk * 256 + tid] = bins[tid];
        }
        gbar(bar);
        // ---- phase B: per-cluster prefix over chunks (block = j) ----
        {
            int* a = (int*)sm;
            int j = blk;
            a[tid] = hist[(size_t)tid * 256 + j];
            __syncthreads();
            for (int d = 1; d < 256; d <<= 1) {
                int v = a[tid];
                int u = (tid >= d) ? a[tid - d] : 0;
                __syncthreads();
                a[tid] = v + u;
                __syncthreads();
            }
            chunkbase[(size_t)tid * 256 + j] = (tid == 0) ? 0 : a[tid - 1];
            if (tid == 255) totals[j] = a[255];
        }
        gbar(bar);
        // ---- phase C: scatter (block = chunk) ----
        {
            int* cb = (int*)sm;
            int* al = (int*)(sm + 1024);
            cb[tid] = totals[tid];
            al[tid] = asn[blk * 256 + tid];
            __syncthreads();
            for (int d = 1; d < 256; d <<= 1) {
                int v = cb[tid];
                int u = (tid >= d) ? cb[tid - d] : 0;
                __syncthreads();
                cb[tid] = v + u;
                __syncthreads();
            }
            int my = al[tid];
            int base = (my == 0) ? 0 : cb[my - 1];
            int r = 0;
            for (int i = 0; i < tid; i++) r += (al[i] == my) ? 1 : 0;
            perm[base + chunkbase[(size_t)blk * 256 + my] + r] = blk * 256 + tid;
        }
        gbar(bar);
        // ---- phase D: ordered sum + update + cc (block = cluster) ----
        {
            int* cb = (int*)sm;
            float (*buf)[STILE][32] = (float (*)[STILE][32])(sm + 1024);
            int j = blk;
            cb[tid] = totals[tid];
            __syncthreads();
            for (int d = 1; d < 256; d <<= 1) {
                int v = cb[tid];
                int u = (tid >= d) ? cb[tid - d] : 0;
                __syncthreads();
                cb[tid] = v + u;
                __syncthreads();
            }
            int base = (j == 0) ? 0 : cb[j - 1];
            int n = totals[j];
            int t = tid & 31, r0 = tid >> 5;
            for (int r = r0; r < STILE; r += 8) {
                if (r < n) buf[0][r][t] = pts[(size_t)perm[base + r] * 32 + t];
            }
            __syncthreads();
            float s = 0.f;
            int b = 0;
            for (int i0 = 0; i0 < n; i0 += STILE, b ^= 1) {
                int nx = i0 + STILE;
                if (nx < n) {
                    for (int r = r0; r < STILE; r += 8) {
                        int g2 = nx + r;
                        if (g2 < n) buf[b ^ 1][r][t] = pts[(size_t)perm[base + g2] * 32 + t];
                    }
                }
                if (tid < 32) {
                    int m = n - i0; if (m > STILE) m = STILE;
                    int i = 0;
                    for (; i + 4 <= m; i += 4) {
                        s = fadd(s, buf[b][i][tid]);
                        s = fadd(s, buf[b][i + 1][tid]);
                        s = fadd(s, buf[b][i + 2][tid]);
                        s = fadd(s, buf[b][i + 3][tid]);
                    }
                    for (; i < m; i++) s = fadd(s, buf[b][i][tid]);
                }
                __syncthreads();
            }
            if (tid < 32) {
                float v;
                if (n > 0) {
                    v = __fdiv_rn(s, (float)n);
                    cent[(size_t)j * 32 + tid] = v;
                } else {
                    v = cent[(size_t)j * 32 + tid];
                }
                float e = fmul(v, v);
                e = fadd(e, __shfl_xor(e, 16));
                e = fadd(e, __shfl_xor(e, 8));
                e = fadd(e, __shfl_xor(e, 4));
                e = fadd(e, __shfl_xor(e, 2));
                e = fadd(e, __shfl_xor(e, 1));
                if (tid == 0) cc[j] = e;
            }
        }
        gbar(bar);
    }
}

// ---------- key assign + L1: conflict-free (pad 36 + interleave) ----
__global__ __launch_bounds__(256) void kdist4p(const float* __restrict__ pts,
        const float* __restrict__ cent, const float* __restrict__ cc,
        float* __restrict__ kd) {
    __shared__ float sc[256 * 36];
    __shared__ float scc[256];
    int tid = threadIdx.x, c = blockIdx.x;
    {
        const float4* c4 = (const float4*)cent;
        for (int i = tid; i < 256 * 8; i += 256) {
            int row = i >> 3, t = i & 7;
            ((float4*)(sc + row * 36))[t] = c4[i];
        }
    }
    scc[tid] = cc[tid];
    __syncthreads();
    int pg = tid >> 2, quarter = tid & 3;
    int pb = c * 256 + pg * 4;
    float x[4][32];
    float xp[4];
    #pragma unroll
    for (int i = 0; i < 4; i++) {
        const float4* pp = (const float4*)(pts + (size_t)(pb + i) * 32);
        #pragma unroll
        for (int t = 0; t < 8; t++) {
            float4 f = pp[t];
            x[i][4*t] = f.x; x[i][4*t+1] = f.y; x[i][4*t+2] = f.z; x[i][4*t+3] = f.w;
        }
        float e[32];
        #pragma unroll
        for (int t = 0; t < 32; t++) e[t] = fmul(x[i][t], x[i][t]);
        xp[i] = sum32_np(e);
    }
    float bd[4] = {3.4e38f, 3.4e38f, 3.4e38f, 3.4e38f};
    int bj[4] = {0x7fffffff, 0x7fffffff, 0x7fffffff, 0x7fffffff};
    for (int jj = 0; jj < 64; jj++) {
        int j = (jj << 2) | quarter;
        const float4* cj = (const float4*)(sc + j * 36);
        float w[32];
        #pragma unroll
        for (int t = 0; t < 8; t++) {
            float4 f = cj[t];
            w[4*t] = f.x; w[4*t+1] = f.y; w[4*t+2] = f.z; w[4*t+3] = f.w;
        }
        float sj = scc[j];
        #pragma unroll
        for (int i = 0; i < 4; i++) {
            float g = 0.f;
            #pragma unroll
            for (int t = 0; t < 32; t++) g = __builtin_fmaf(x[i][t], w[t], g);
            float d = fadd(fsub(xp[i], fmul(2.f, g)), sj);
            if (d < bd[i]) { bd[i] = d; bj[i] = j; }
        }
    }
    // lexicographic (d, j) combine across the 4 quarters
    #pragma unroll
    for (int i = 0; i < 4; i++) {
        float ob; int oj;
        ob = __shfl_xor(bd[i], 1); oj = __shfl_xor(bj[i], 1);
        if (ob < bd[i] || (ob == bd[i] && oj < bj[i])) { bd[i] = ob; bj[i] = oj; }
        ob = __shfl_xor(bd[i], 2); oj = __shfl_xor(bj[i], 2);
        if (ob < bd[i] || (ob == bd[i] && oj < bj[i])) { bd[i] = ob; bj[i] = oj; }
    }
    if (quarter == 0) {
        #pragma unroll
        for (int i = 0; i < 4; i++) {
            const float* cb = &sc[bj[i] * 36];
            float e[32];
            #pragma unroll
            for (int t = 0; t < 32; t++) e[t] = fabsf(fsub(cb[t], x[i][t]));
            kd[pb + i] = sum32_np(e);
        }
    }
}

// ---------- top-256 via bit-descent select (exact stable set) -------
__global__ __launch_bounds__(256) void topk_v3(const float* __restrict__ kd,
        const float* __restrict__ k_t, const float* __restrict__ v_t,
        float* __restrict__ ksel, float* __restrict__ vsel) {
    __shared__ int wsum[4];
    __shared__ int sc1[256];
    __shared__ int out_src[256];
    int bh = blockIdx.x, tid = threadIdx.x;
    int wave = tid >> 6, lane = tid & 63;
    unsigned uv[16];
    {
        const unsigned* kdu = (const unsigned*)(kd + (size_t)bh * 4096);
        #pragma unroll
        for (int q = 0; q < 16; q++) uv[q] = kdu[tid * 16 + q];
    }
    unsigned T = 0u;
    for (int bit = 31; bit >= 0; bit--) {
        unsigned cand = T | (1u << bit);
        int c = 0;
        #pragma unroll
        for (int q = 0; q < 16; q++) c += (uv[q] >= cand) ? 1 : 0;
        c += __shfl_xor(c, 32); c += __shfl_xor(c, 16); c += __shfl_xor(c, 8);
        c += __shfl_xor(c, 4);  c += __shfl_xor(c, 2);  c += __shfl_xor(c, 1);
        if (lane == 0) wsum[wave] = c;
        __syncthreads();
        int tot = wsum[0] + wsum[1] + wsum[2] + wsum[3];
        __syncthreads();
        if (tot >= 256) T = cand;
    }
    int r;
    {
        int c = 0;
        #pragma unroll
        for (int q = 0; q < 16; q++) c += (uv[q] > T) ? 1 : 0;
        c += __shfl_xor(c, 32); c += __shfl_xor(c, 16); c += __shfl_xor(c, 8);
        c += __shfl_xor(c, 4);  c += __shfl_xor(c, 2);  c += __shfl_xor(c, 1);
        if (lane == 0) wsum[wave] = c;
        __syncthreads();
        r = 256 - (wsum[0] + wsum[1] + wsum[2] + wsum[3]);
        __syncthreads();
    }
    int ec = 0;
    #pragma unroll
    for (int q = 0; q < 16; q++) ec += (uv[q] == T) ? 1 : 0;
    sc1[tid] = ec;
    __syncthreads();
    for (int d = 1; d < 256; d <<= 1) {
        int t0 = sc1[tid];
        int u0 = (tid >= d) ? sc1[tid - d] : 0;
        __syncthreads();
        sc1[tid] = t0 + u0;
        __syncthreads();
    }
    int erank = (tid == 0) ? 0 : sc1[tid - 1];
    __syncthreads();
    bool incl[16];
    int ic = 0;
    #pragma unroll
    for (int q = 0; q < 16; q++) {
        unsigned u = uv[q];
        bool inc;
        if (u > T) inc = true;
        else if (u == T) { inc = (erank < r); erank++; }
        else inc = false;
        incl[q] = inc;
        ic += inc ? 1 : 0;
    }
    sc1[tid] = ic;
    __syncthreads();
    for (int d = 1; d < 256; d <<= 1) {
        int t0 = sc1[tid];
        int u0 = (tid >= d) ? sc1[tid - d] : 0;
        __syncthreads();
        sc1[tid] = t0 + u0;
        __syncthreads();
    }
    int pos = (tid == 0) ? 0 : sc1[tid - 1];
    int base_i = tid * 16;
    #pragma unroll
    for (int q = 0; q < 16; q++) {
        if (incl[q]) out_src[pos++] = base_i + q;
    }
    __syncthreads();
    for (int e = tid; e < 256 * 32; e += 256) {
        int jj = e >> 5, t = e & 31;
        int src = out_src[jj];
        ksel[(size_t)bh * 8192 + e] = k_t[((size_t)bh * 4096 + src) * 32 + t];
        vsel[(size_t)bh * 8192 + e] = v_t[((size_t)bh * 4096 + src) * 32 + t];
    }
}

// ---------- attention v4: 8-thread groups (4 slices x 2 dh), Q=4 ----
#define HP4 2052
__global__ __launch_bounds__(256, 2) void attn_v4(const float* __restrict__ q_t,
        const float* __restrict__ ksel, const float* __restrict__ vsel,
        float* __restrict__ out) {
    __shared__ float sk[4 * HP4];
    __shared__ float sv[4 * HP4];
    int bh = blockIdx.y, tid = threadIdx.x;
    {
        const float4* gk = (const float4*)(ksel + (size_t)bh * 8192);
        const float4* gv = (const float4*)(vsel + (size_t)bh * 8192);
        for (int i = tid; i < 2048; i += 256) {
            int s = i >> 9, idx = i & 511;
            ((float4*)(sk + s * HP4))[idx] = gk[i];
            ((float4*)(sv + s * HP4))[idx] = gv[i];
        }
    }
    __syncthreads();
    int grp = tid >> 3;              // 32 groups of 8 lanes
    int dh = tid & 1;                // dim half
    int slice = (tid >> 1) & 3;      // key quarter
    int p0 = bh * 4096 + blockIdx.x * 128 + grp * 4;
    float q[4][16];
    #pragma unroll
    for (int i = 0; i < 4; i++) {
        const float4* qp = (const float4*)(q_t + (size_t)(p0 + i) * 32 + dh * 16);
        #pragma unroll
        for (int t = 0; t < 4; t++) {
            float4 f = qp[t];
            q[i][4*t] = f.x; q[i][4*t+1] = f.y; q[i][4*t+2] = f.z; q[i][4*t+3] = f.w;
        }
    }
    float o[4][16];
    #pragma unroll
    for (int i = 0; i < 4; i++)
        #pragma unroll
        for (int t = 0; t < 16; t++) o[i][t] = 0.f;
    float ls[4] = {0.f, 0.f, 0.f, 0.f};
    const float* kb = sk + slice * HP4 + dh * 16;
    const float* vb = sv + slice * HP4 + dh * 16;
    for (int j = 0; j < 64; j++) {
        float kf[16];
        #pragma unroll
        for (int t = 0; t < 4; t++) {
            float4 f = *(const float4*)(kb + j * 32 + t * 4);
            kf[4*t] = f.x; kf[4*t+1] = f.y; kf[4*t+2] = f.z; kf[4*t+3] = f.w;
        }
        float ps[4];
        #pragma unroll
        for (int i = 0; i < 4; i++) {
            float a = 0.f, b2 = 0.f, c2 = 0.f, d2 = 0.f;
            #pragma unroll
            for (int t = 0; t < 4; t++) {
                a  += q[i][4*t]   * kf[4*t];
                b2 += q[i][4*t+1] * kf[4*t+1];
                c2 += q[i][4*t+2] * kf[4*t+2];
                d2 += q[i][4*t+3] * kf[4*t+3];
            }
            ps[i] = (a + b2) + (c2 + d2);
        }
        #pragma unroll
        for (int i = 0; i < 4; i++) ps[i] += __shfl_xor(ps[i], 1);  // dh combine
        float w[4];
        #pragma unroll
        for (int i = 0; i < 4; i++) {
            w[i] = __expf(ps[i] - 1.0f);
            ls[i] += w[i];
        }
        float vf[16];
        #pragma unroll
        for (int t = 0; t < 4; t++) {
            float4 f = *(const float4*)(vb + j * 32 + t * 4);
            vf[4*t] = f.x; vf[4*t+1] = f.y; vf[4*t+2] = f.z; vf[4*t+3] = f.w;
        }
        #pragma unroll
        for (int i = 0; i < 4; i++)
            #pragma unroll
            for (int t = 0; t < 16; t++) o[i][t] += w[i] * vf[t];
    }
    // combine the 4 key slices (tree: (s0+s1)+(s2+s3))
    #pragma unroll
    for (int i = 0; i < 4; i++) {
        #pragma unroll
        for (int t = 0; t < 16; t++) {
            o[i][t] += __shfl_xor(o[i][t], 2);
            o[i][t] += __shfl_xor(o[i][t], 4);
        }
        ls[i] += __shfl_xor(ls[i], 2);
        ls[i] += __shfl_xor(ls[i], 4);
    }
    if (slice == 0) {
        #pragma unroll
        for (int i = 0; i < 4; i++) {
            float inv = 1.f / ls[i];
            float4* op = (float4*)(out + (size_t)(p0 + i) * 32 + dh * 16);
            #pragma unroll
            for (int t = 0; t < 4; t++)
                op[t] = make_float4(o[i][4*t]*inv, o[i][4*t+1]*inv,
                                    o[i][4*t+2]*inv, o[i][4*t+3]*inv);
        }
    }
}

// ---------- unfold (bh,L,32) -> (b,256,L) ---------------------------
__global__ __launch_bounds__(256) void unfold_kernel(const float* __restrict__ att,
        float* __restrict__ Fo) {
    __shared__ float tbuf[32][65];
    int bh = blockIdx.y, l0 = blockIdx.x * 64;
    int b = bh >> 3, h = bh & 7;
    int tid = threadIdx.x;
    #pragma unroll
    for (int r = 0; r < 8; r++) {
        int e = r * 256 + tid;
        int l = e >> 5, d = e & 31;
        tbuf[d][l] = att[((size_t)bh * 4096 + l0 + l) * 32 + d];
    }
    __syncthreads();
    #pragma unroll
    for (int r = 0; r < 8; r++) {
        int e = r * 256 + tid;
        int d = e >> 6, l = e & 63;
        Fo[((size_t)b * 256 + h * 32 + d) * LSEQ + l0 + l] = tbuf[d][l];
    }
}

// ---------- final LN + scale + residual, LDS-cached (numpy orders) --
__global__ __launch_bounds__(64) void lnres_np(const float* __restrict__ x,
        const float* __restrict__ g, const float* __restrict__ bt,
        const float* __restrict__ gs, const float* __restrict__ qsrc,
        float* __restrict__ y) {
    __shared__ float xl[256 * 64];
    __shared__ float ql[256 * 64];
    int tid = threadIdx.x;
    int gid = blockIdx.x * 64 + tid;
    int b = gid >> 12, l = gid & 4095;
    const float* xb = x + (size_t)b * CDIM * LSEQ + l;
    const float* qb = qsrc + (size_t)b * CDIM * LSEQ + l;
    #pragma unroll 8
    for (int c = 0; c < 256; c++) {
        gld_lds4(xb + (size_t)c * LSEQ, xl + c * 64);
        gld_lds4(qb + (size_t)c * LSEQ, ql + c * 64);
    }
    __syncthreads();
    float s = 0.f;
    #pragma unroll 8
    for (int c = 0; c < 256; c++) s = fadd(s, xl[c * 64 + tid]);
    float mean = __fdiv_rn(s, 256.f);
    float s2 = 0.f;
    #pragma unroll 8
    for (int c = 0; c < 256; c++) {
        float d = fsub(xl[c * 64 + tid], mean);
        s2 = fadd(s2, fmul(d, d));
    }
    float var = __fdiv_rn(s2, 256.f);
    float den = fadd(__fsqrt_rn(var), 1e-6f);
    float scale = gs[0];
    float* yb = y + (size_t)b * CDIM * LSEQ + l;
    #pragma unroll 4
    for (int c = 0; c < 256; c++) {
        float d = fsub(xl[c * 64 + tid], mean);
        float r = fadd(__fdiv_rn(fmul(g[c], d), den), bt[c]);
        yb[(size_t)c * LSEQ] = fadd(fmul(scale, r), ql[c * 64 + tid]);
    }
}

// ==================================================================
extern "C" void kernel_launch(void* const* d_in, const int* in_sizes, int n_in,
                              void* d_out, int out_size, void* d_ws, size_t ws_size,
                              hipStream_t stream) {
    const float* qsrc   = (const float*)d_in[0];
    const float* ctx    = (const float*)d_in[1];
    const float* w_q    = (const float*)d_in[2];
    const float* w_kv   = (const float*)d_in[3];
    const float* w_out  = (const float*)d_in[4];
    const float* g_ctx  = (const float*)d_in[5];
    const float* b_ctx  = (const float*)d_in[6];
    const float* g_q    = (const float*)d_in[7];
    const float* b_q    = (const float*)d_in[8];
    const float* g_out  = (const float*)d_in[9];
    const float* b_out  = (const float*)d_in[10];
    const float* gs     = (const float*)d_in[11];

    char* base = (char*)d_ws;
    const size_t MB = 1024 * 1024;
    float* yln   = (float*)base;               // [0,8) ctx LN; later att
    float* att   = (float*)base;
    float* kvbuf = (float*)(base + 8 * MB);    // [8,24) kv conv; later y32
    float* y32   = (float*)(base + 8 * MB);
    float* qbuf  = (float*)(base + 24 * MB);   // [24,32) q conv; later Fo
    float* Fo    = (float*)(base + 24 * MB);
    float* q_t   = (float*)(base + 32 * MB);   // [32,40)
    float* k_t   = (float*)(base + 40 * MB);   // [40,48)
    float* v_t   = (float*)(base + 48 * MB);   // [48,56)
    char* SM = base + 56 * MB;
    float* xx_q      = (float*)(SM + 0);            // 256 KB
    float* cent      = (float*)(SM + 512 * 1024);   // 32 KB
    float* cc        = (float*)(SM + 576 * 1024);   // 1 KB
    int*   totals    = (int*)  (SM + 640 * 1024);   // 1 KB
    int*   bar       = (int*)  (SM + 648 * 1024);   // 4 B (barrier counter)
    int*   asn       = (int*)  (SM + 704 * 1024);   // 256 KB
    int*   hist      = (int*)  (SM + 960 * 1024);   // 256 KB
    int*   chunkbase = (int*)  (SM + 1472 * 1024);  // 256 KB
    int*   perm      = (int*)  (SM + 1984 * 1024);  // 256 KB
    float* kd        = (float*)(SM + 2240 * 1024);  // 256 KB
    float* ksel      = (float*)(SM + 2496 * 1024);  // 512 KB
    float* vsel      = (float*)(SM + 3008 * 1024);  // 512 KB
    float* yln_q     = (float*)(base + 60 * MB);    // [60,68) q LN out

    ln2_np<<<256, 64, 0, stream>>>(ctx, g_ctx, b_ctx, yln,
                                   qsrc, g_q, b_q, yln_q);
    conv_all16<<<dim3(8, 48, 2), 256, 0, stream>>>(w_kv, yln, kvbuf,
                                                   w_q, yln_q, qbuf);
    fold3_np<<<768, 256, 0, stream>>>(kvbuf, qbuf, k_t, v_t, q_t, xx_q, cent, cc);

    hipMemsetAsync(bar, 0, sizeof(int), stream);
    kmeans_fused<<<256, 256, 0, stream>>>(q_t, xx_q, cent, cc, asn, hist,
                                          chunkbase, totals, perm, bar, 10);

    kdist4p<<<256, 256, 0, stream>>>(k_t, cent, cc, kd);
    topk_v3<<<16, 256, 0, stream>>>(kd, k_t, v_t, ksel, vsel);
    attn_v4<<<dim3(32, 16), 256, 0, stream>>>(q_t, ksel, vsel, att);
    unfold_kernel<<<dim3(64, 16), 256, 0, stream>>>(att, Fo);
    conv_q8<false><<<dim3(4, 32, 2), 256, 0, stream>>>(w_out, Fo, y32);
    lnres_np<<<128, 64, 0, stream>>>(y32, g_out, b_out, gs, qsrc, (float*)d_out);
}

// Round 13
// 834.733 us; speedup vs baseline: 1.8485x; 1.8485x over previous
//
#include <hip/hip_runtime.h>
#include <math.h>

#define CDIM 256
#define LSEQ 4096
#define NBH 16
#define NPTS 65536
#define KC 256

__device__ __forceinline__ float fadd(float a, float b){ return __fadd_rn(a,b); }
__device__ __forceinline__ float fmul(float a, float b){ return __fmul_rn(a,b); }
__device__ __forceinline__ float fsub(float a, float b){ return __fsub_rn(a,b); }

// async global->LDS, width 4: per-lane global src, wave-uniform LDS base,
// lane i lands at base + i*4 (guide §5 / m03)
__device__ __forceinline__ void gld_lds4(const float* g, float* l){
    __builtin_amdgcn_global_load_lds(
        (const __attribute__((address_space(1))) unsigned int*)g,
        (__attribute__((address_space(3))) unsigned int*)l, 4, 0, 0);
}

// numpy contiguous n=32 float32 sum, AVX-512 npyv path (verified R5)
__device__ __forceinline__ float sum32_np(const float* e){
    float l[16];
    #pragma unroll
    for (int j = 0; j < 16; j++) l[j] = fadd(e[j], e[j + 16]);
    float t3[8];
    #pragma unroll
    for (int j = 0; j < 8; j++) t3[j] = fadd(l[j], l[j + 8]);
    float t6[4];
    #pragma unroll
    for (int j = 0; j < 4; j++) t6[j] = fadd(t3[j], t3[j + 4]);
    return fadd(fadd(t6[0], t6[2]), fadd(t6[1], t6[3]));
}

// ---------- both LayerNorms, LDS-cached (numpy exact per position) --
__global__ __launch_bounds__(64) void ln2_np(
        const float* __restrict__ x0, const float* __restrict__ g0,
        const float* __restrict__ bt0, float* __restrict__ y0,
        const float* __restrict__ x1, const float* __restrict__ g1,
        const float* __restrict__ bt1, float* __restrict__ y1) {
    __shared__ float xl[256 * 64];
    int tid = threadIdx.x;
    int gid = blockIdx.x * 64 + tid;
    int which = gid >> 13;
    int r = gid & 8191;
    int b = r >> 12, l = r & 4095;
    const float* x  = which ? x1 : x0;
    const float* g  = which ? g1 : g0;
    const float* bt = which ? bt1 : bt0;
    float* y        = which ? y1 : y0;
    const float* xb = x + (size_t)b * CDIM * LSEQ + l;
    #pragma unroll 8
    for (int c = 0; c < 256; c++)
        gld_lds4(xb + (size_t)c * LSEQ, xl + c * 64);
    __syncthreads();
    float s = 0.f;
    #pragma unroll 8
    for (int c = 0; c < 256; c++) s = fadd(s, xl[c * 64 + tid]);
    float mean = __fdiv_rn(s, 256.f);
    float s2 = 0.f;
    #pragma unroll 8
    for (int c = 0; c < 256; c++) {
        float d = fsub(xl[c * 64 + tid], mean);
        s2 = fadd(s2, fmul(d, d));
    }
    float var = __fdiv_rn(s2, 256.f);
    float den = fadd(__fsqrt_rn(var), 1e-6f);
    float* yb = y + (size_t)b * CDIM * LSEQ + l;
    #pragma unroll 4
    for (int c = 0; c < 256; c++) {
        float d = fsub(xl[c * 64 + tid], mean);
        yb[(size_t)c * LSEQ] = fadd(__fdiv_rn(fmul(g[c], d), den), bt[c]);
    }
}

// ---------- fused conv (kv + q), COT=16, NL=2, no LDS (R6 = 58.5us) -
__global__ __launch_bounds__(256) void conv_all16(
        const float* __restrict__ Wkv, const float* __restrict__ Xkv,
        float* __restrict__ Ykv,
        const float* __restrict__ Wq, const float* __restrict__ Xq,
        float* __restrict__ Yq) {
    int tid = threadIdx.x;
    int l0 = blockIdx.x * 512 + tid * 2;
    bool qpath = blockIdx.y >= 32;
    int yb = qpath ? (blockIdx.y - 32) : blockIdx.y;
    int o0 = yb * 16;
    int b = blockIdx.z;
    const float4* w4 = (const float4*)((qpath ? Wq : Wkv) + (size_t)o0 * CDIM);
    const float* X = qpath ? Xq : Xkv;
    const float* xb = X + (size_t)b * CDIM * LSEQ;
    float acc[16][2];
    #pragma unroll
    for (int oo = 0; oo < 16; oo++) { acc[oo][0] = 0.f; acc[oo][1] = 0.f; }
    bool sop = qpath || (blockIdx.y < 16);
    if (sop) {
        for (int c = 0; c < 256; c += 4) {
            float2 x0q = *(const float2*)(xb + (size_t)(c + 0) * LSEQ + l0);
            float2 x1q = *(const float2*)(xb + (size_t)(c + 1) * LSEQ + l0);
            float2 x2q = *(const float2*)(xb + (size_t)(c + 2) * LSEQ + l0);
            float2 x3q = *(const float2*)(xb + (size_t)(c + 3) * LSEQ + l0);
            #pragma unroll
            for (int oo = 0; oo < 16; oo++) {
                float4 w = w4[(oo * 256 + c) >> 2];
                acc[oo][0] = fadd(acc[oo][0], fmul(w.x, x0q.x));
                acc[oo][0] = fadd(acc[oo][0], fmul(w.y, x1q.x));
                acc[oo][0] = fadd(acc[oo][0], fmul(w.z, x2q.x));
                acc[oo][0] = fadd(acc[oo][0], fmul(w.w, x3q.x));
                acc[oo][1] = fadd(acc[oo][1], fmul(w.x, x0q.y));
                acc[oo][1] = fadd(acc[oo][1], fmul(w.y, x1q.y));
                acc[oo][1] = fadd(acc[oo][1], fmul(w.z, x2q.y));
                acc[oo][1] = fadd(acc[oo][1], fmul(w.w, x3q.y));
            }
        }
    } else {
        for (int c = 0; c < 256; c += 4) {
            float2 x0q = *(const float2*)(xb + (size_t)(c + 0) * LSEQ + l0);
            float2 x1q = *(const float2*)(xb + (size_t)(c + 1) * LSEQ + l0);
            float2 x2q = *(const float2*)(xb + (size_t)(c + 2) * LSEQ + l0);
            float2 x3q = *(const float2*)(xb + (size_t)(c + 3) * LSEQ + l0);
            #pragma unroll
            for (int oo = 0; oo < 16; oo++) {
                float4 w = w4[(oo * 256 + c) >> 2];
                acc[oo][0] = __builtin_fmaf(w.x, x0q.x, acc[oo][0]);
                acc[oo][0] = __builtin_fmaf(w.y, x1q.x, acc[oo][0]);
                acc[oo][0] = __builtin_fmaf(w.z, x2q.x, acc[oo][0]);
                acc[oo][0] = __builtin_fmaf(w.w, x3q.x, acc[oo][0]);
                acc[oo][1] = __builtin_fmaf(w.x, x0q.y, acc[oo][1]);
                acc[oo][1] = __builtin_fmaf(w.y, x1q.y, acc[oo][1]);
                acc[oo][1] = __builtin_fmaf(w.z, x2q.y, acc[oo][1]);
                acc[oo][1] = __builtin_fmaf(w.w, x3q.y, acc[oo][1]);
            }
        }
    }
    float* Y = qpath ? Yq : Ykv;
    int rows = qpath ? 256 : 512;
    #pragma unroll
    for (int oo = 0; oo < 16; oo++)
        *(float2*)(Y + ((size_t)b * rows + o0 + oo) * LSEQ + l0) =
            make_float2(acc[oo][0], acc[oo][1]);
}

// ---------- conv 256-row: COT=8, NL=4, LDS (exact R4 version) -------
template<bool EXACT>
__global__ __launch_bounds__(256) void conv_q8(const float* __restrict__ W,
        const float* __restrict__ X, float* __restrict__ Y) {
    __shared__ float ws[8 * 256];
    int tid = threadIdx.x;
    int l0 = blockIdx.x * 1024 + tid * 4;
    int o0 = blockIdx.y * 8;
    int b = blockIdx.z;
    {
        const float4* wb4 = (const float4*)(W + (size_t)o0 * CDIM);
        float4* ws4s = (float4*)ws;
        for (int i = tid; i < 8 * 64; i += 256) ws4s[i] = wb4[i];
    }
    __syncthreads();
    const float* xb = X + (size_t)b * CDIM * LSEQ;
    float acc[8][4];
    #pragma unroll
    for (int oo = 0; oo < 8; oo++)
        #pragma unroll
        for (int i = 0; i < 4; i++) acc[oo][i] = 0.f;
    const float4* ws4 = (const float4*)ws;
    for (int c = 0; c < 256; c += 4) {
        float4 x0q = *(const float4*)(xb + (size_t)(c + 0) * LSEQ + l0);
        float4 x1q = *(const float4*)(xb + (size_t)(c + 1) * LSEQ + l0);
        float4 x2q = *(const float4*)(xb + (size_t)(c + 2) * LSEQ + l0);
        float4 x3q = *(const float4*)(xb + (size_t)(c + 3) * LSEQ + l0);
        #pragma unroll
        for (int oo = 0; oo < 8; oo++) {
            float4 w = ws4[(oo * 256 + c) >> 2];
            if (EXACT) {
                acc[oo][0] = fadd(acc[oo][0], fmul(w.x, x0q.x));
                acc[oo][0] = fadd(acc[oo][0], fmul(w.y, x1q.x));
                acc[oo][0] = fadd(acc[oo][0], fmul(w.z, x2q.x));
                acc[oo][0] = fadd(acc[oo][0], fmul(w.w, x3q.x));
                acc[oo][1] = fadd(acc[oo][1], fmul(w.x, x0q.y));
                acc[oo][1] = fadd(acc[oo][1], fmul(w.y, x1q.y));
                acc[oo][1] = fadd(acc[oo][1], fmul(w.z, x2q.y));
                acc[oo][1] = fadd(acc[oo][1], fmul(w.w, x3q.y));
                acc[oo][2] = fadd(acc[oo][2], fmul(w.x, x0q.z));
                acc[oo][2] = fadd(acc[oo][2], fmul(w.y, x1q.z));
                acc[oo][2] = fadd(acc[oo][2], fmul(w.z, x2q.z));
                acc[oo][2] = fadd(acc[oo][2], fmul(w.w, x3q.z));
                acc[oo][3] = fadd(acc[oo][3], fmul(w.x, x0q.w));
                acc[oo][3] = fadd(acc[oo][3], fmul(w.y, x1q.w));
                acc[oo][3] = fadd(acc[oo][3], fmul(w.z, x2q.w));
                acc[oo][3] = fadd(acc[oo][3], fmul(w.w, x3q.w));
            } else {
                acc[oo][0] = __builtin_fmaf(w.x, x0q.x, acc[oo][0]);
                acc[oo][0] = __builtin_fmaf(w.y, x1q.x, acc[oo][0]);
                acc[oo][0] = __builtin_fmaf(w.z, x2q.x, acc[oo][0]);
                acc[oo][0] = __builtin_fmaf(w.w, x3q.x, acc[oo][0]);
                acc[oo][1] = __builtin_fmaf(w.x, x0q.y, acc[oo][1]);
                acc[oo][1] = __builtin_fmaf(w.y, x1q.y, acc[oo][1]);
                acc[oo][1] = __builtin_fmaf(w.z, x2q.y, acc[oo][1]);
                acc[oo][1] = __builtin_fmaf(w.w, x3q.y, acc[oo][1]);
                acc[oo][2] = __builtin_fmaf(w.x, x0q.z, acc[oo][2]);
                acc[oo][2] = __builtin_fmaf(w.y, x1q.z, acc[oo][2]);
                acc[oo][2] = __builtin_fmaf(w.z, x2q.z, acc[oo][2]);
                acc[oo][2] = __builtin_fmaf(w.w, x3q.z, acc[oo][2]);
                acc[oo][3] = __builtin_fmaf(w.x, x0q.w, acc[oo][3]);
                acc[oo][3] = __builtin_fmaf(w.y, x1q.w, acc[oo][3]);
                acc[oo][3] = __builtin_fmaf(w.z, x2q.w, acc[oo][3]);
                acc[oo][3] = __builtin_fmaf(w.w, x3q.w, acc[oo][3]);
            }
        }
    }
    #pragma unroll
    for (int oo = 0; oo < 8; oo++)
        *(float4*)(Y + ((size_t)b * 256 + o0 + oo) * LSEQ + l0) =
            make_float4(acc[oo][0], acc[oo][1], acc[oo][2], acc[oo][3]);
}

// ---------- fold x3 (k norm, v plain, q norm+xx+cent/cc) ------------
__device__ __forceinline__ void fold_body(const float* __restrict__ src,
        int srcRows, int row0, int donorm, float* __restrict__ dst,
        float* __restrict__ xxout, float* __restrict__ centout,
        float* __restrict__ ccout, int p) {
    int bh = p >> 12, l = p & 4095;
    int b = bh >> 3, h = bh & 7;
    const float* sp = src + ((size_t)b * srcRows + row0 + h * 32) * LSEQ + l;
    float x[32];
    #pragma unroll
    for (int t = 0; t < 32; t++) x[t] = sp[(size_t)t * LSEQ];
    float4* dp4 = (float4*)(dst + (size_t)p * 32);
    if (donorm) {
        float ss = 0.f;
        #pragma unroll
        for (int t = 0; t < 32; t++) ss = fadd(ss, fmul(x[t], x[t]));
        float n = __fsqrt_rn(ss);
        float den = fmaxf(n, 1e-12f);
        #pragma unroll
        for (int t = 0; t < 32; t++) x[t] = __fdiv_rn(x[t], den);
    }
    #pragma unroll
    for (int t = 0; t < 8; t++)
        dp4[t] = make_float4(x[4*t], x[4*t+1], x[4*t+2], x[4*t+3]);
    if (xxout) {
        float e[32];
        #pragma unroll
        for (int t = 0; t < 32; t++) e[t] = fmul(x[t], x[t]);
        float xv = sum32_np(e);
        xxout[p] = xv;
        if (centout && p < KC) {
            float4* cp4 = (float4*)(centout + (size_t)p * 32);
            #pragma unroll
            for (int t = 0; t < 8; t++)
                cp4[t] = make_float4(x[4*t], x[4*t+1], x[4*t+2], x[4*t+3]);
            ccout[p] = xv;
        }
    }
}

__global__ __launch_bounds__(256) void fold3_np(const float* __restrict__ kvbuf,
        const float* __restrict__ qbuf, float* __restrict__ k_t,
        float* __restrict__ v_t, float* __restrict__ q_t,
        float* __restrict__ xx, float* __restrict__ cent, float* __restrict__ cc) {
    int blk = blockIdx.x, tid = threadIdx.x;
    if (blk < 256) {
        fold_body(kvbuf, 512, 0, 1, k_t, nullptr, nullptr, nullptr, blk * 256 + tid);
    } else if (blk < 512) {
        fold_body(kvbuf, 512, 256, 0, v_t, nullptr, nullptr, nullptr, (blk - 256) * 256 + tid);
    } else {
        fold_body(qbuf, 256, 0, 1, q_t, xx, cent, cc, (blk - 512) * 256 + tid);
    }
}

// ---------- argmin over HALF the clusters, conflict-free LDS --------
__global__ __launch_bounds__(256) void assign_h(const float* __restrict__ pts,
        const float* __restrict__ xx, const float* __restrict__ cent,
        const float* __restrict__ cc, float* __restrict__ bdg, int* __restrict__ bjg) {
    __shared__ float sc[128 * 36];
    __shared__ float scc[128];
    int tid = threadIdx.x;
    int c = blockIdx.x >> 1, h = blockIdx.x & 1;
    {
        const float4* c4 = (const float4*)(cent + (size_t)h * 128 * 32);
        for (int i = tid; i < 128 * 8; i += 256) {
            int row = i >> 3, t = i & 7;
            ((float4*)(sc + row * 36))[t] = c4[i];
        }
    }
    if (tid < 128) scc[tid] = cc[h * 128 + tid];
    __syncthreads();
    int pg = tid >> 2, quarter = tid & 3;
    int pb = c * 256 + pg * 4;
    float x[4][32];
    float xp[4];
    #pragma unroll
    for (int i = 0; i < 4; i++) {
        const float4* pp = (const float4*)(pts + (size_t)(pb + i) * 32);
        #pragma unroll
        for (int t = 0; t < 8; t++) {
            float4 f = pp[t];
            x[i][4*t] = f.x; x[i][4*t+1] = f.y; x[i][4*t+2] = f.z; x[i][4*t+3] = f.w;
        }
        xp[i] = xx[pb + i];
    }
    float bd[4] = {3.4e38f, 3.4e38f, 3.4e38f, 3.4e38f};
    int bj[4] = {0x7fffffff, 0x7fffffff, 0x7fffffff, 0x7fffffff};
    for (int jj = 0; jj < 32; jj++) {
        int j = (jj << 2) | quarter;
        const float4* cj = (const float4*)(sc + j * 36);
        float w[32];
        #pragma unroll
        for (int t = 0; t < 8; t++) {
            float4 f = cj[t];
            w[4*t] = f.x; w[4*t+1] = f.y; w[4*t+2] = f.z; w[4*t+3] = f.w;
        }
        float sj = scc[j];
        int jg = h * 128 + j;
        #pragma unroll
        for (int i = 0; i < 4; i++) {
            float g = 0.f;
            #pragma unroll
            for (int t = 0; t < 32; t++) g = __builtin_fmaf(x[i][t], w[t], g);
            float d = fadd(fsub(xp[i], fmul(2.f, g)), sj);
            if (d < bd[i]) { bd[i] = d; bj[i] = jg; }
        }
    }
    // lexicographic (d, j) combine across the 4 quarters
    #pragma unroll
    for (int i = 0; i < 4; i++) {
        float ob; int oj;
        ob = __shfl_xor(bd[i], 1); oj = __shfl_xor(bj[i], 1);
        if (ob < bd[i] || (ob == bd[i] && oj < bj[i])) { bd[i] = ob; bj[i] = oj; }
        ob = __shfl_xor(bd[i], 2); oj = __shfl_xor(bj[i], 2);
        if (ob < bd[i] || (ob == bd[i] && oj < bj[i])) { bd[i] = ob; bj[i] = oj; }
    }
    if (quarter == 0) {
        #pragma unroll
        for (int i = 0; i < 4; i++) {
            bdg[(size_t)h * NPTS + pb + i] = bd[i];
            bjg[(size_t)h * NPTS + pb + i] = bj[i];
        }
    }
}

// ---------- merge halves -> asn + hist (tie prefers half0 = lower j)-
__global__ __launch_bounds__(256) void merge_asn(const float* __restrict__ bdg,
        const int* __restrict__ bjg, int* __restrict__ asn, int* __restrict__ hist) {
    __shared__ int bins[256];
    int tid = threadIdx.x, c = blockIdx.x;
    bins[tid] = 0;
    __syncthreads();
    int p = c * 256 + tid;
    float d0 = bdg[p], d1 = bdg[NPTS + p];
    int j = (d1 < d0) ? bjg[NPTS + p] : bjg[p];
    asn[p] = j;
    atomicAdd(&bins[j], 1);
    __syncthreads();
    hist[c * 256 + tid] = bins[tid];
}

// ---------- per-cluster prefix over 256 chunks ----------------------
__global__ __launch_bounds__(256) void scan_chunks(const int* __restrict__ hist,
        int* __restrict__ chunkbase, int* __restrict__ totals) {
    __shared__ int a[256];
    int j = blockIdx.x, c = threadIdx.x;
    a[c] = hist[(size_t)c * 256 + j];
    __syncthreads();
    for (int d = 1; d < 256; d <<= 1) {
        int v = a[c];
        int u = (c >= d) ? a[c - d] : 0;
        __syncthreads();
        a[c] = v + u;
        __syncthreads();
    }
    chunkbase[(size_t)c * 256 + j] = (c == 0) ? 0 : a[c - 1];
    if (c == 255) totals[j] = a[255];
}

// ---------- scatter: parallel cbase scan + stable rank --------------
__global__ __launch_bounds__(256) void scatter_v5(const int* __restrict__ asn,
        const int* __restrict__ chunkbase, const int* __restrict__ totals,
        int* __restrict__ perm) {
    __shared__ int cb[256];
    __shared__ int al[256];
    int c = blockIdx.x, tid = threadIdx.x;
    cb[tid] = totals[tid];
    al[tid] = asn[c * 256 + tid];
    __syncthreads();
    for (int d = 1; d < 256; d <<= 1) {
        int v = cb[tid];
        int u = (tid >= d) ? cb[tid - d] : 0;
        __syncthreads();
        cb[tid] = v + u;
        __syncthreads();
    }
    int my = al[tid];
    int base = (my == 0) ? 0 : cb[my - 1];
    int r = 0;
    for (int i = 0; i < tid; i++) r += (al[i] == my) ? 1 : 0;
    perm[base + chunkbase[(size_t)c * 256 + my] + r] = c * 256 + tid;
}

// ---------- ordered sum + update + cc (parallel cbase scan) ---------
#define STILE 128
__global__ __launch_bounds__(256) void sumk_v4(const float* __restrict__ pts,
        const int* __restrict__ perm, const int* __restrict__ totals,
        float* __restrict__ cent, float* __restrict__ cc) {
    __shared__ int cb[256];
    __shared__ float buf[2][STILE][32];
    int j = blockIdx.x, tid = threadIdx.x;
    cb[tid] = totals[tid];
    __syncthreads();
    for (int d = 1; d < 256; d <<= 1) {
        int v = cb[tid];
        int u = (tid >= d) ? cb[tid - d] : 0;
        __syncthreads();
        cb[tid] = v + u;
        __syncthreads();
    }
    int base = (j == 0) ? 0 : cb[j - 1];
    int n = totals[j];
    int t = tid & 31, r0 = tid >> 5;
    for (int r = r0; r < STILE; r += 8) {
        if (r < n) buf[0][r][t] = pts[(size_t)perm[base + r] * 32 + t];
    }
    __syncthreads();
    float s = 0.f;
    int b = 0;
    for (int i0 = 0; i0 < n; i0 += STILE, b ^= 1) {
        int nx = i0 + STILE;
        if (nx < n) {
            for (int r = r0; r < STILE; r += 8) {
                int g = nx + r;
                if (g < n) buf[b ^ 1][r][t] = pts[(size_t)perm[base + g] * 32 + t];
            }
        }
        if (tid < 32) {
            int m = n - i0; if (m > STILE) m = STILE;
            int i = 0;
            for (; i + 4 <= m; i += 4) {
                s = fadd(s, buf[b][i][tid]);
                s = fadd(s, buf[b][i + 1][tid]);
                s = fadd(s, buf[b][i + 2][tid]);
                s = fadd(s, buf[b][i + 3][tid]);
            }
            for (; i < m; i++) s = fadd(s, buf[b][i][tid]);
        }
        __syncthreads();
    }
    if (tid < 32) {
        float v;
        if (n > 0) {
            v = __fdiv_rn(s, (float)n);
            cent[(size_t)j * 32 + tid] = v;
        } else {
            v = cent[(size_t)j * 32 + tid];
        }
        float e = fmul(v, v);
        e = fadd(e, __shfl_xor(e, 16));
        e = fadd(e, __shfl_xor(e, 8));
        e = fadd(e, __shfl_xor(e, 4));
        e = fadd(e, __shfl_xor(e, 2));
        e = fadd(e, __shfl_xor(e, 1));
        if (tid == 0) cc[j] = e;
    }
}

// ---------- key assign + L1: conflict-free (pad 36 + interleave) ----
__global__ __launch_bounds__(256) void kdist4p(const float* __restrict__ pts,
        const float* __restrict__ cent, const float* __restrict__ cc,
        float* __restrict__ kd) {
    __shared__ float sc[256 * 36];
    __shared__ float scc[256];
    int tid = threadIdx.x, c = blockIdx.x;
    {
        const float4* c4 = (const float4*)cent;
        for (int i = tid; i < 256 * 8; i += 256) {
            int row = i >> 3, t = i & 7;
            ((float4*)(sc + row * 36))[t] = c4[i];
        }
    }
    scc[tid] = cc[tid];
    __syncthreads();
    int pg = tid >> 2, quarter = tid & 3;
    int pb = c * 256 + pg * 4;
    float x[4][32];
    float xp[4];
    #pragma unroll
    for (int i = 0; i < 4; i++) {
        const float4* pp = (const float4*)(pts + (size_t)(pb + i) * 32);
        #pragma unroll
        for (int t = 0; t < 8; t++) {
            float4 f = pp[t];
            x[i][4*t] = f.x; x[i][4*t+1] = f.y; x[i][4*t+2] = f.z; x[i][4*t+3] = f.w;
        }
        float e[32];
        #pragma unroll
        for (int t = 0; t < 32; t++) e[t] = fmul(x[i][t], x[i][t]);
        xp[i] = sum32_np(e);
    }
    float bd[4] = {3.4e38f, 3.4e38f, 3.4e38f, 3.4e38f};
    int bj[4] = {0x7fffffff, 0x7fffffff, 0x7fffffff, 0x7fffffff};
    for (int jj = 0; jj < 64; jj++) {
        int j = (jj << 2) | quarter;
        const float4* cj = (const float4*)(sc + j * 36);
        float w[32];
        #pragma unroll
        for (int t = 0; t < 8; t++) {
            float4 f = cj[t];
            w[4*t] = f.x; w[4*t+1] = f.y; w[4*t+2] = f.z; w[4*t+3] = f.w;
        }
        float sj = scc[j];
        #pragma unroll
        for (int i = 0; i < 4; i++) {
            float g = 0.f;
            #pragma unroll
            for (int t = 0; t < 32; t++) g = __builtin_fmaf(x[i][t], w[t], g);
            float d = fadd(fsub(xp[i], fmul(2.f, g)), sj);
            if (d < bd[i]) { bd[i] = d; bj[i] = j; }
        }
    }
    // lexicographic (d, j) combine across the 4 quarters
    #pragma unroll
    for (int i = 0; i < 4; i++) {
        float ob; int oj;
        ob = __shfl_xor(bd[i], 1); oj = __shfl_xor(bj[i], 1);
        if (ob < bd[i] || (ob == bd[i] && oj < bj[i])) { bd[i] = ob; bj[i] = oj; }
        ob = __shfl_xor(bd[i], 2); oj = __shfl_xor(bj[i], 2);
        if (ob < bd[i] || (ob == bd[i] && oj < bj[i])) { bd[i] = ob; bj[i] = oj; }
    }
    if (quarter == 0) {
        #pragma unroll
        for (int i = 0; i < 4; i++) {
            const float* cb = &sc[bj[i] * 36];
            float e[32];
            #pragma unroll
            for (int t = 0; t < 32; t++) e[t] = fabsf(fsub(cb[t], x[i][t]));
            kd[pb + i] = sum32_np(e);
        }
    }
}

// ---------- top-256 via bit-descent select (exact stable set) -------
__global__ __launch_bounds__(256) void topk_v3(const float* __restrict__ kd,
        const float* __restrict__ k_t, const float* __restrict__ v_t,
        float* __restrict__ ksel, float* __restrict__ vsel) {
    __shared__ int wsum[4];
    __shared__ int sc1[256];
    __shared__ int out_src[256];
    int bh = blockIdx.x, tid = threadIdx.x;
    int wave = tid >> 6, lane = tid & 63;
    unsigned uv[16];
    {
        const unsigned* kdu = (const unsigned*)(kd + (size_t)bh * 4096);
        #pragma unroll
        for (int q = 0; q < 16; q++) uv[q] = kdu[tid * 16 + q];
    }
    unsigned T = 0u;
    for (int bit = 31; bit >= 0; bit--) {
        unsigned cand = T | (1u << bit);
        int c = 0;
        #pragma unroll
        for (int q = 0; q < 16; q++) c += (uv[q] >= cand) ? 1 : 0;
        c += __shfl_xor(c, 32); c += __shfl_xor(c, 16); c += __shfl_xor(c, 8);
        c += __shfl_xor(c, 4);  c += __shfl_xor(c, 2);  c += __shfl_xor(c, 1);
        if (lane == 0) wsum[wave] = c;
        __syncthreads();
        int tot = wsum[0] + wsum[1] + wsum[2] + wsum[3];
        __syncthreads();
        if (tot >= 256) T = cand;
    }
    int r;
    {
        int c = 0;
        #pragma unroll
        for (int q = 0; q < 16; q++) c += (uv[q] > T) ? 1 : 0;
        c += __shfl_xor(c, 32); c += __shfl_xor(c, 16); c += __shfl_xor(c, 8);
        c += __shfl_xor(c, 4);  c += __shfl_xor(c, 2);  c += __shfl_xor(c, 1);
        if (lane == 0) wsum[wave] = c;
        __syncthreads();
        r = 256 - (wsum[0] + wsum[1] + wsum[2] + wsum[3]);
        __syncthreads();
    }
    int ec = 0;
    #pragma unroll
    for (int q = 0; q < 16; q++) ec += (uv[q] == T) ? 1 : 0;
    sc1[tid] = ec;
    __syncthreads();
    for (int d = 1; d < 256; d <<= 1) {
        int t0 = sc1[tid];
        int u0 = (tid >= d) ? sc1[tid - d] : 0;
        __syncthreads();
        sc1[tid] = t0 + u0;
        __syncthreads();
    }
    int erank = (tid == 0) ? 0 : sc1[tid - 1];
    __syncthreads();
    bool incl[16];
    int ic = 0;
    #pragma unroll
    for (int q = 0; q < 16; q++) {
        unsigned u = uv[q];
        bool inc;
        if (u > T) inc = true;
        else if (u == T) { inc = (erank < r); erank++; }
        else inc = false;
        incl[q] = inc;
        ic += inc ? 1 : 0;
    }
    sc1[tid] = ic;
    __syncthreads();
    for (int d = 1; d < 256; d <<= 1) {
        int t0 = sc1[tid];
        int u0 = (tid >= d) ? sc1[tid - d] : 0;
        __syncthreads();
        sc1[tid] = t0 + u0;
        __syncthreads();
    }
    int pos = (tid == 0) ? 0 : sc1[tid - 1];
    int base_i = tid * 16;
    #pragma unroll
    for (int q = 0; q < 16; q++) {
        if (incl[q]) out_src[pos++] = base_i + q;
    }
    __syncthreads();
    for (int e = tid; e < 256 * 32; e += 256) {
        int jj = e >> 5, t = e & 31;
        int src = out_src[jj];
        ksel[(size_t)bh * 8192 + e] = k_t[((size_t)bh * 4096 + src) * 32 + t];
        vsel[(size_t)bh * 8192 + e] = v_t[((size_t)bh * 4096 + src) * 32 + t];
    }
}

// ---------- attention v4: 8-thread groups (4 slices x 2 dh), Q=4 ----
#define HP4 2052
__global__ __launch_bounds__(256, 2) void attn_v4(const float* __restrict__ q_t,
        const float* __restrict__ ksel, const float* __restrict__ vsel,
        float* __restrict__ out) {
    __shared__ float sk[4 * HP4];
    __shared__ float sv[4 * HP4];
    int bh = blockIdx.y, tid = threadIdx.x;
    {
        const float4* gk = (const float4*)(ksel + (size_t)bh * 8192);
        const float4* gv = (const float4*)(vsel + (size_t)bh * 8192);
        for (int i = tid; i < 2048; i += 256) {
            int s = i >> 9, idx = i & 511;
            ((float4*)(sk + s * HP4))[idx] = gk[i];
            ((float4*)(sv + s * HP4))[idx] = gv[i];
        }
    }
    __syncthreads();
    int grp = tid >> 3;              // 32 groups of 8 lanes
    int dh = tid & 1;                // dim half
    int slice = (tid >> 1) & 3;      // key quarter
    int p0 = bh * 4096 + blockIdx.x * 128 + grp * 4;
    float q[4][16];
    #pragma unroll
    for (int i = 0; i < 4; i++) {
        const float4* qp = (const float4*)(q_t + (size_t)(p0 + i) * 32 + dh * 16);
        #pragma unroll
        for (int t = 0; t < 4; t++) {
            float4 f = qp[t];
            q[i][4*t] = f.x; q[i][4*t+1] = f.y; q[i][4*t+2] = f.z; q[i][4*t+3] = f.w;
        }
    }
    float o[4][16];
    #pragma unroll
    for (int i = 0; i < 4; i++)
        #pragma unroll
        for (int t = 0; t < 16; t++) o[i][t] = 0.f;
    float ls[4] = {0.f, 0.f, 0.f, 0.f};
    const float* kb = sk + slice * HP4 + dh * 16;
    const float* vb = sv + slice * HP4 + dh * 16;
    for (int j = 0; j < 64; j++) {
        float kf[16];
        #pragma unroll
        for (int t = 0; t < 4; t++) {
            float4 f = *(const float4*)(kb + j * 32 + t * 4);
            kf[4*t] = f.x; kf[4*t+1] = f.y; kf[4*t+2] = f.z; kf[4*t+3] = f.w;
        }
        float ps[4];
        #pragma unroll
        for (int i = 0; i < 4; i++) {
            float a = 0.f, b2 = 0.f, c2 = 0.f, d2 = 0.f;
            #pragma unroll
            for (int t = 0; t < 4; t++) {
                a  += q[i][4*t]   * kf[4*t];
                b2 += q[i][4*t+1] * kf[4*t+1];
                c2 += q[i][4*t+2] * kf[4*t+2];
                d2 += q[i][4*t+3] * kf[4*t+3];
            }
            ps[i] = (a + b2) + (c2 + d2);
        }
        #pragma unroll
        for (int i = 0; i < 4; i++) ps[i] += __shfl_xor(ps[i], 1);  // dh combine
        float w[4];
        #pragma unroll
        for (int i = 0; i < 4; i++) {
            w[i] = __expf(ps[i] - 1.0f);
            ls[i] += w[i];
        }
        float vf[16];
        #pragma unroll
        for (int t = 0; t < 4; t++) {
            float4 f = *(const float4*)(vb + j * 32 + t * 4);
            vf[4*t] = f.x; vf[4*t+1] = f.y; vf[4*t+2] = f.z; vf[4*t+3] = f.w;
        }
        #pragma unroll
        for (int i = 0; i < 4; i++)
            #pragma unroll
            for (int t = 0; t < 16; t++) o[i][t] += w[i] * vf[t];
    }
    // combine the 4 key slices (tree: (s0+s1)+(s2+s3))
    #pragma unroll
    for (int i = 0; i < 4; i++) {
        #pragma unroll
        for (int t = 0; t < 16; t++) {
            o[i][t] += __shfl_xor(o[i][t], 2);
            o[i][t] += __shfl_xor(o[i][t], 4);
        }
        ls[i] += __shfl_xor(ls[i], 2);
        ls[i] += __shfl_xor(ls[i], 4);
    }
    if (slice == 0) {
        #pragma unroll
        for (int i = 0; i < 4; i++) {
            float inv = 1.f / ls[i];
            float4* op = (float4*)(out + (size_t)(p0 + i) * 32 + dh * 16);
            #pragma unroll
            for (int t = 0; t < 4; t++)
                op[t] = make_float4(o[i][4*t]*inv, o[i][4*t+1]*inv,
                                    o[i][4*t+2]*inv, o[i][4*t+3]*inv);
        }
    }
}

// ---------- unfold (bh,L,32) -> (b,256,L) ---------------------------
__global__ __launch_bounds__(256) void unfold_kernel(const float* __restrict__ att,
        float* __restrict__ Fo) {
    __shared__ float tbuf[32][65];
    int bh = blockIdx.y, l0 = blockIdx.x * 64;
    int b = bh >> 3, h = bh & 7;
    int tid = threadIdx.x;
    #pragma unroll
    for (int r = 0; r < 8; r++) {
        int e = r * 256 + tid;
        int l = e >> 5, d = e & 31;
        tbuf[d][l] = att[((size_t)bh * 4096 + l0 + l) * 32 + d];
    }
    __syncthreads();
    #pragma unroll
    for (int r = 0; r < 8; r++) {
        int e = r * 256 + tid;
        int d = e >> 6, l = e & 63;
        Fo[((size_t)b * 256 + h * 32 + d) * LSEQ + l0 + l] = tbuf[d][l];
    }
}

// ---------- final LN + scale + residual, LDS-cached (numpy orders) --
__global__ __launch_bounds__(64) void lnres_np(const float* __restrict__ x,
        const float* __restrict__ g, const float* __restrict__ bt,
        const float* __restrict__ gs, const float* __restrict__ qsrc,
        float* __restrict__ y) {
    __shared__ float xl[256 * 64];
    __shared__ float ql[256 * 64];
    int tid = threadIdx.x;
    int gid = blockIdx.x * 64 + tid;
    int b = gid >> 12, l = gid & 4095;
    const float* xb = x + (size_t)b * CDIM * LSEQ + l;
    const float* qb = qsrc + (size_t)b * CDIM * LSEQ + l;
    #pragma unroll 8
    for (int c = 0; c < 256; c++) {
        gld_lds4(xb + (size_t)c * LSEQ, xl + c * 64);
        gld_lds4(qb + (size_t)c * LSEQ, ql + c * 64);
    }
    __syncthreads();
    float s = 0.f;
    #pragma unroll 8
    for (int c = 0; c < 256; c++) s = fadd(s, xl[c * 64 + tid]);
    float mean = __fdiv_rn(s, 256.f);
    float s2 = 0.f;
    #pragma unroll 8
    for (int c = 0; c < 256; c++) {
        float d = fsub(xl[c * 64 + tid], mean);
        s2 = fadd(s2, fmul(d, d));
    }
    float var = __fdiv_rn(s2, 256.f);
    float den = fadd(__fsqrt_rn(var), 1e-6f);
    float scale = gs[0];
    float* yb = y + (size_t)b * CDIM * LSEQ + l;
    #pragma unroll 4
    for (int c = 0; c < 256; c++) {
        float d = fsub(xl[c * 64 + tid], mean);
        float r = fadd(__fdiv_rn(fmul(g[c], d), den), bt[c]);
        yb[(size_t)c * LSEQ] = fadd(fmul(scale, r), ql[c * 64 + tid]);
    }
}

// ==================================================================
extern "C" void kernel_launch(void* const* d_in, const int* in_sizes, int n_in,
                              void* d_out, int out_size, void* d_ws, size_t ws_size,
                              hipStream_t stream) {
    const float* qsrc   = (const float*)d_in[0];
    const float* ctx    = (const float*)d_in[1];
    const float* w_q    = (const float*)d_in[2];
    const float* w_kv   = (const float*)d_in[3];
    const float* w_out  = (const float*)d_in[4];
    const float* g_ctx  = (const float*)d_in[5];
    const float* b_ctx  = (const float*)d_in[6];
    const float* g_q    = (const float*)d_in[7];
    const float* b_q    = (const float*)d_in[8];
    const float* g_out  = (const float*)d_in[9];
    const float* b_out  = (const float*)d_in[10];
    const float* gs     = (const float*)d_in[11];

    char* base = (char*)d_ws;
    const size_t MB = 1024 * 1024;
    float* yln   = (float*)base;               // [0,8) ctx LN; later att
    float* att   = (float*)base;
    float* kvbuf = (float*)(base + 8 * MB);    // [8,24) kv conv; later bdg/bjg; later y32
    float* y32   = (float*)(base + 8 * MB);
    float* bdg   = (float*)(base + 8 * MB);    // 512 KB (2*NPTS floats) during k-means
    int*   bjg   = (int*)  (base + 9 * MB);    // 512 KB during k-means
    float* qbuf  = (float*)(base + 24 * MB);   // [24,32) q conv; later Fo
    float* Fo    = (float*)(base + 24 * MB);
    float* q_t   = (float*)(base + 32 * MB);   // [32,40)
    float* k_t   = (float*)(base + 40 * MB);   // [40,48)
    float* v_t   = (float*)(base + 48 * MB);   // [48,56)
    char* SM = base + 56 * MB;
    float* xx_q      = (float*)(SM + 0);            // 256 KB
    float* cent      = (float*)(SM + 512 * 1024);   // 32 KB
    float* cc        = (float*)(SM + 576 * 1024);   // 1 KB
    int*   totals    = (int*)  (SM + 640 * 1024);   // 1 KB
    int*   asn       = (int*)  (SM + 704 * 1024);   // 256 KB
    int*   hist      = (int*)  (SM + 960 * 1024);   // 256 KB
    int*   chunkbase = (int*)  (SM + 1472 * 1024);  // 256 KB
    int*   perm      = (int*)  (SM + 1984 * 1024);  // 256 KB
    float* kd        = (float*)(SM + 2240 * 1024);  // 256 KB
    float* ksel      = (float*)(SM + 2496 * 1024);  // 512 KB
    float* vsel      = (float*)(SM + 3008 * 1024);  // 512 KB
    float* yln_q     = (float*)(base + 60 * MB);    // [60,68) q LN out

    ln2_np<<<256, 64, 0, stream>>>(ctx, g_ctx, b_ctx, yln,
                                   qsrc, g_q, b_q, yln_q);
    conv_all16<<<dim3(8, 48, 2), 256, 0, stream>>>(w_kv, yln, kvbuf,
                                                   w_q, yln_q, qbuf);
    fold3_np<<<768, 256, 0, stream>>>(kvbuf, qbuf, k_t, v_t, q_t, xx_q, cent, cc);

    for (int it = 0; it < 10; it++) {
        assign_h<<<512, 256, 0, stream>>>(q_t, xx_q, cent, cc, bdg, bjg);
        merge_asn<<<256, 256, 0, stream>>>(bdg, bjg, asn, hist);
        scan_chunks<<<256, 256, 0, stream>>>(hist, chunkbase, totals);
        scatter_v5<<<256, 256, 0, stream>>>(asn, chunkbase, totals, perm);
        sumk_v4<<<256, 256, 0, stream>>>(q_t, perm, totals, cent, cc);
    }

    kdist4p<<<256, 256, 0, stream>>>(k_t, cent, cc, kd);
    topk_v3<<<16, 256, 0, stream>>>(kd, k_t, v_t, ksel, vsel);
    attn_v4<<<dim3(32, 16), 256, 0, stream>>>(q_t, ksel, vsel, att);
    unfold_kernel<<<dim3(64, 16), 256, 0, stream>>>(att, Fo);
    conv_q8<false><<<dim3(4, 32, 2), 256, 0, stream>>>(w_out, Fo, y32);
    lnres_np<<<128, 64, 0, stream>>>(y32, g_out, b_out, gs, qsrc, (float*)d_out);
}

// Round 14
// 832.640 us; speedup vs baseline: 1.8531x; 1.0025x over previous
//
#include <hip/hip_runtime.h>
#include <math.h>

#define CDIM 256
#define LSEQ 4096
#define NBH 16
#define NPTS 65536
#define KC 256

typedef float v2f __attribute__((ext_vector_type(2)));

__device__ __forceinline__ float fadd(float a, float b){ return __fadd_rn(a,b); }
__device__ __forceinline__ float fmul(float a, float b){ return __fmul_rn(a,b); }
__device__ __forceinline__ float fsub(float a, float b){ return __fsub_rn(a,b); }

// async global->LDS, width 4: per-lane global src, wave-uniform LDS base,
// lane i lands at base + i*4 (guide §5 / m03)
__device__ __forceinline__ void gld_lds4(const float* g, float* l){
    __builtin_amdgcn_global_load_lds(
        (const __attribute__((address_space(1))) unsigned int*)g,
        (__attribute__((address_space(3))) unsigned int*)l, 4, 0, 0);
}

// numpy contiguous n=32 float32 sum, AVX-512 npyv path (verified R5)
__device__ __forceinline__ float sum32_np(const float* e){
    float l[16];
    #pragma unroll
    for (int j = 0; j < 16; j++) l[j] = fadd(e[j], e[j + 16]);
    float t3[8];
    #pragma unroll
    for (int j = 0; j < 8; j++) t3[j] = fadd(l[j], l[j + 8]);
    float t6[4];
    #pragma unroll
    for (int j = 0; j < 4; j++) t6[j] = fadd(t3[j], t3[j + 4]);
    return fadd(fadd(t6[0], t6[2]), fadd(t6[1], t6[3]));
}

// ---------- both LayerNorms, LDS-cached (numpy exact per position) --
__global__ __launch_bounds__(64) void ln2_np(
        const float* __restrict__ x0, const float* __restrict__ g0,
        const float* __restrict__ bt0, float* __restrict__ y0,
        const float* __restrict__ x1, const float* __restrict__ g1,
        const float* __restrict__ bt1, float* __restrict__ y1) {
    __shared__ float xl[256 * 64];
    int tid = threadIdx.x;
    int gid = blockIdx.x * 64 + tid;
    int which = gid >> 13;
    int r = gid & 8191;
    int b = r >> 12, l = r & 4095;
    const float* x  = which ? x1 : x0;
    const float* g  = which ? g1 : g0;
    const float* bt = which ? bt1 : bt0;
    float* y        = which ? y1 : y0;
    const float* xb = x + (size_t)b * CDIM * LSEQ + l;
    #pragma unroll 8
    for (int c = 0; c < 256; c++)
        gld_lds4(xb + (size_t)c * LSEQ, xl + c * 64);
    __syncthreads();
    float s = 0.f;
    #pragma unroll 8
    for (int c = 0; c < 256; c++) s = fadd(s, xl[c * 64 + tid]);
    float mean = __fdiv_rn(s, 256.f);
    float s2 = 0.f;
    #pragma unroll 8
    for (int c = 0; c < 256; c++) {
        float d = fsub(xl[c * 64 + tid], mean);
        s2 = fadd(s2, fmul(d, d));
    }
    float var = __fdiv_rn(s2, 256.f);
    float den = fadd(__fsqrt_rn(var), 1e-6f);
    float* yb = y + (size_t)b * CDIM * LSEQ + l;
    #pragma unroll 4
    for (int c = 0; c < 256; c++) {
        float d = fsub(xl[c * 64 + tid], mean);
        yb[(size_t)c * LSEQ] = fadd(__fdiv_rn(fmul(g[c], d), den), bt[c]);
    }
}

// ---------- fused conv (kv + q), COT=16, NL=2, packed f32 -----------
// v2f (ext_vector) acc + explicit pk mul/add (SOP) or pk fma (v rows):
// v_pk_*_f32 executes both lanes per instruction, each component
// IEEE-RN identical to the scalar op -> bit-identical, half the
// VALU instruction count (R13 floor ~34us scalar -> ~17us packed).
__global__ __launch_bounds__(256) void conv_all16(
        const float* __restrict__ Wkv, const float* __restrict__ Xkv,
        float* __restrict__ Ykv,
        const float* __restrict__ Wq, const float* __restrict__ Xq,
        float* __restrict__ Yq) {
    int tid = threadIdx.x;
    int l0 = blockIdx.x * 512 + tid * 2;
    bool qpath = blockIdx.y >= 32;
    int yb = qpath ? (blockIdx.y - 32) : blockIdx.y;
    int o0 = yb * 16;
    int b = blockIdx.z;
    const float4* w4 = (const float4*)((qpath ? Wq : Wkv) + (size_t)o0 * CDIM);
    const float* X = qpath ? Xq : Xkv;
    const float* xb = X + (size_t)b * CDIM * LSEQ;
    v2f acc[16];
    #pragma unroll
    for (int oo = 0; oo < 16; oo++) acc[oo] = (v2f){0.f, 0.f};
    bool sop = qpath || (blockIdx.y < 16);
    if (sop) {
        for (int c = 0; c < 256; c += 4) {
            v2f x0q = *(const v2f*)(xb + (size_t)(c + 0) * LSEQ + l0);
            v2f x1q = *(const v2f*)(xb + (size_t)(c + 1) * LSEQ + l0);
            v2f x2q = *(const v2f*)(xb + (size_t)(c + 2) * LSEQ + l0);
            v2f x3q = *(const v2f*)(xb + (size_t)(c + 3) * LSEQ + l0);
            #pragma unroll
            for (int oo = 0; oo < 16; oo++) {
                float4 w = w4[(oo * 256 + c) >> 2];
                acc[oo] = acc[oo] + (v2f){w.x, w.x} * x0q;
                acc[oo] = acc[oo] + (v2f){w.y, w.y} * x1q;
                acc[oo] = acc[oo] + (v2f){w.z, w.z} * x2q;
                acc[oo] = acc[oo] + (v2f){w.w, w.w} * x3q;
            }
        }
    } else {
        for (int c = 0; c < 256; c += 4) {
            v2f x0q = *(const v2f*)(xb + (size_t)(c + 0) * LSEQ + l0);
            v2f x1q = *(const v2f*)(xb + (size_t)(c + 1) * LSEQ + l0);
            v2f x2q = *(const v2f*)(xb + (size_t)(c + 2) * LSEQ + l0);
            v2f x3q = *(const v2f*)(xb + (size_t)(c + 3) * LSEQ + l0);
            #pragma unroll
            for (int oo = 0; oo < 16; oo++) {
                float4 w = w4[(oo * 256 + c) >> 2];
                acc[oo] = __builtin_elementwise_fma((v2f){w.x, w.x}, x0q, acc[oo]);
                acc[oo] = __builtin_elementwise_fma((v2f){w.y, w.y}, x1q, acc[oo]);
                acc[oo] = __builtin_elementwise_fma((v2f){w.z, w.z}, x2q, acc[oo]);
                acc[oo] = __builtin_elementwise_fma((v2f){w.w, w.w}, x3q, acc[oo]);
            }
        }
    }
    float* Y = qpath ? Yq : Ykv;
    int rows = qpath ? 256 : 512;
    #pragma unroll
    for (int oo = 0; oo < 16; oo++)
        *(v2f*)(Y + ((size_t)b * rows + o0 + oo) * LSEQ + l0) = acc[oo];
}

// ---------- conv 256-row: COT=8, NL=4, LDS, packed f32 --------------
template<bool EXACT>
__global__ __launch_bounds__(256) void conv_q8(const float* __restrict__ W,
        const float* __restrict__ X, float* __restrict__ Y) {
    __shared__ float ws[8 * 256];
    int tid = threadIdx.x;
    int l0 = blockIdx.x * 1024 + tid * 4;
    int o0 = blockIdx.y * 8;
    int b = blockIdx.z;
    {
        const float4* wb4 = (const float4*)(W + (size_t)o0 * CDIM);
        float4* ws4s = (float4*)ws;
        for (int i = tid; i < 8 * 64; i += 256) ws4s[i] = wb4[i];
    }
    __syncthreads();
    const float* xb = X + (size_t)b * CDIM * LSEQ;
    v2f acc[8][2];
    #pragma unroll
    for (int oo = 0; oo < 8; oo++) {
        acc[oo][0] = (v2f){0.f, 0.f};
        acc[oo][1] = (v2f){0.f, 0.f};
    }
    const float4* ws4 = (const float4*)ws;
    for (int c = 0; c < 256; c += 4) {
        float4 x0q = *(const float4*)(xb + (size_t)(c + 0) * LSEQ + l0);
        float4 x1q = *(const float4*)(xb + (size_t)(c + 1) * LSEQ + l0);
        float4 x2q = *(const float4*)(xb + (size_t)(c + 2) * LSEQ + l0);
        float4 x3q = *(const float4*)(xb + (size_t)(c + 3) * LSEQ + l0);
        v2f x0a = {x0q.x, x0q.y}, x0b = {x0q.z, x0q.w};
        v2f x1a = {x1q.x, x1q.y}, x1b = {x1q.z, x1q.w};
        v2f x2a = {x2q.x, x2q.y}, x2b = {x2q.z, x2q.w};
        v2f x3a = {x3q.x, x3q.y}, x3b = {x3q.z, x3q.w};
        #pragma unroll
        for (int oo = 0; oo < 8; oo++) {
            float4 w = ws4[(oo * 256 + c) >> 2];
            if (EXACT) {
                acc[oo][0] = acc[oo][0] + (v2f){w.x, w.x} * x0a;
                acc[oo][1] = acc[oo][1] + (v2f){w.x, w.x} * x0b;
                acc[oo][0] = acc[oo][0] + (v2f){w.y, w.y} * x1a;
                acc[oo][1] = acc[oo][1] + (v2f){w.y, w.y} * x1b;
                acc[oo][0] = acc[oo][0] + (v2f){w.z, w.z} * x2a;
                acc[oo][1] = acc[oo][1] + (v2f){w.z, w.z} * x2b;
                acc[oo][0] = acc[oo][0] + (v2f){w.w, w.w} * x3a;
                acc[oo][1] = acc[oo][1] + (v2f){w.w, w.w} * x3b;
            } else {
                acc[oo][0] = __builtin_elementwise_fma((v2f){w.x, w.x}, x0a, acc[oo][0]);
                acc[oo][1] = __builtin_elementwise_fma((v2f){w.x, w.x}, x0b, acc[oo][1]);
                acc[oo][0] = __builtin_elementwise_fma((v2f){w.y, w.y}, x1a, acc[oo][0]);
                acc[oo][1] = __builtin_elementwise_fma((v2f){w.y, w.y}, x1b, acc[oo][1]);
                acc[oo][0] = __builtin_elementwise_fma((v2f){w.z, w.z}, x2a, acc[oo][0]);
                acc[oo][1] = __builtin_elementwise_fma((v2f){w.z, w.z}, x2b, acc[oo][1]);
                acc[oo][0] = __builtin_elementwise_fma((v2f){w.w, w.w}, x3a, acc[oo][0]);
                acc[oo][1] = __builtin_elementwise_fma((v2f){w.w, w.w}, x3b, acc[oo][1]);
            }
        }
    }
    #pragma unroll
    for (int oo = 0; oo < 8; oo++)
        *(float4*)(Y + ((size_t)b * 256 + o0 + oo) * LSEQ + l0) =
            make_float4(acc[oo][0][0], acc[oo][0][1], acc[oo][1][0], acc[oo][1][1]);
}

// ---------- fold x3 (k norm, v plain, q norm+xx+cent/cc) ------------
__device__ __forceinline__ void fold_body(const float* __restrict__ src,
        int srcRows, int row0, int donorm, float* __restrict__ dst,
        float* __restrict__ xxout, float* __restrict__ centout,
        float* __restrict__ ccout, int p) {
    int bh = p >> 12, l = p & 4095;
    int b = bh >> 3, h = bh & 7;
    const float* sp = src + ((size_t)b * srcRows + row0 + h * 32) * LSEQ + l;
    float x[32];
    #pragma unroll
    for (int t = 0; t < 32; t++) x[t] = sp[(size_t)t * LSEQ];
    float4* dp4 = (float4*)(dst + (size_t)p * 32);
    if (donorm) {
        float ss = 0.f;
        #pragma unroll
        for (int t = 0; t < 32; t++) ss = fadd(ss, fmul(x[t], x[t]));
        float n = __fsqrt_rn(ss);
        float den = fmaxf(n, 1e-12f);
        #pragma unroll
        for (int t = 0; t < 32; t++) x[t] = __fdiv_rn(x[t], den);
    }
    #pragma unroll
    for (int t = 0; t < 8; t++)
        dp4[t] = make_float4(x[4*t], x[4*t+1], x[4*t+2], x[4*t+3]);
    if (xxout) {
        float e[32];
        #pragma unroll
        for (int t = 0; t < 32; t++) e[t] = fmul(x[t], x[t]);
        float xv = sum32_np(e);
        xxout[p] = xv;
        if (centout && p < KC) {
            float4* cp4 = (float4*)(centout + (size_t)p * 32);
            #pragma unroll
            for (int t = 0; t < 8; t++)
                cp4[t] = make_float4(x[4*t], x[4*t+1], x[4*t+2], x[4*t+3]);
            ccout[p] = xv;
        }
    }
}

__global__ __launch_bounds__(256) void fold3_np(const float* __restrict__ kvbuf,
        const float* __restrict__ qbuf, float* __restrict__ k_t,
        float* __restrict__ v_t, float* __restrict__ q_t,
        float* __restrict__ xx, float* __restrict__ cent, float* __restrict__ cc) {
    int blk = blockIdx.x, tid = threadIdx.x;
    if (blk < 256) {
        fold_body(kvbuf, 512, 0, 1, k_t, nullptr, nullptr, nullptr, blk * 256 + tid);
    } else if (blk < 512) {
        fold_body(kvbuf, 512, 256, 0, v_t, nullptr, nullptr, nullptr, (blk - 256) * 256 + tid);
    } else {
        fold_body(qbuf, 256, 0, 1, q_t, xx, cent, cc, (blk - 512) * 256 + tid);
    }
}

// ---------- argmin over HALF the clusters, conflict-free + packed ---
// Points packed pairwise into v2f: per-component fma chain (ascending
// t) identical to scalar -> bit-identical distances; selection scalar.
__global__ __launch_bounds__(256) void assign_h(const float* __restrict__ pts,
        const float* __restrict__ xx, const float* __restrict__ cent,
        const float* __restrict__ cc, float* __restrict__ bdg, int* __restrict__ bjg) {
    __shared__ float sc[128 * 36];
    __shared__ float scc[128];
    int tid = threadIdx.x;
    int c = blockIdx.x >> 1, h = blockIdx.x & 1;
    {
        const float4* c4 = (const float4*)(cent + (size_t)h * 128 * 32);
        for (int i = tid; i < 128 * 8; i += 256) {
            int row = i >> 3, t = i & 7;
            ((float4*)(sc + row * 36))[t] = c4[i];
        }
    }
    if (tid < 128) scc[tid] = cc[h * 128 + tid];
    __syncthreads();
    int pg = tid >> 2, quarter = tid & 3;
    int pb = c * 256 + pg * 4;
    v2f xp2[2][32];
    float xp[4];
    #pragma unroll
    for (int i = 0; i < 4; i++) {
        const float4* pp = (const float4*)(pts + (size_t)(pb + i) * 32);
        #pragma unroll
        for (int t = 0; t < 8; t++) {
            float4 f = pp[t];
            xp2[i >> 1][4*t+0][i & 1] = f.x;
            xp2[i >> 1][4*t+1][i & 1] = f.y;
            xp2[i >> 1][4*t+2][i & 1] = f.z;
            xp2[i >> 1][4*t+3][i & 1] = f.w;
        }
        xp[i] = xx[pb + i];
    }
    float bd[4] = {3.4e38f, 3.4e38f, 3.4e38f, 3.4e38f};
    int bj[4] = {0x7fffffff, 0x7fffffff, 0x7fffffff, 0x7fffffff};
    for (int jj = 0; jj < 32; jj++) {
        int j = (jj << 2) | quarter;
        const float4* cj = (const float4*)(sc + j * 36);
        float w[32];
        #pragma unroll
        for (int t = 0; t < 8; t++) {
            float4 f = cj[t];
            w[4*t] = f.x; w[4*t+1] = f.y; w[4*t+2] = f.z; w[4*t+3] = f.w;
        }
        float sj = scc[j];
        int jg = h * 128 + j;
        v2f g0 = {0.f, 0.f}, g1 = {0.f, 0.f};
        #pragma unroll
        for (int t = 0; t < 32; t++) {
            v2f wv = {w[t], w[t]};
            g0 = __builtin_elementwise_fma(xp2[0][t], wv, g0);
            g1 = __builtin_elementwise_fma(xp2[1][t], wv, g1);
        }
        #pragma unroll
        for (int i = 0; i < 4; i++) {
            float g = (i < 2) ? g0[i & 1] : g1[i & 1];
            float d = fadd(fsub(xp[i], fmul(2.f, g)), sj);
            if (d < bd[i]) { bd[i] = d; bj[i] = jg; }
        }
    }
    // lexicographic (d, j) combine across the 4 quarters
    #pragma unroll
    for (int i = 0; i < 4; i++) {
        float ob; int oj;
        ob = __shfl_xor(bd[i], 1); oj = __shfl_xor(bj[i], 1);
        if (ob < bd[i] || (ob == bd[i] && oj < bj[i])) { bd[i] = ob; bj[i] = oj; }
        ob = __shfl_xor(bd[i], 2); oj = __shfl_xor(bj[i], 2);
        if (ob < bd[i] || (ob == bd[i] && oj < bj[i])) { bd[i] = ob; bj[i] = oj; }
    }
    if (quarter == 0) {
        #pragma unroll
        for (int i = 0; i < 4; i++) {
            bdg[(size_t)h * NPTS + pb + i] = bd[i];
            bjg[(size_t)h * NPTS + pb + i] = bj[i];
        }
    }
}

// ---------- merge halves -> asn + hist (tie prefers half0 = lower j)-
__global__ __launch_bounds__(256) void merge_asn(const float* __restrict__ bdg,
        const int* __restrict__ bjg, int* __restrict__ asn, int* __restrict__ hist) {
    __shared__ int bins[256];
    int tid = threadIdx.x, c = blockIdx.x;
    bins[tid] = 0;
    __syncthreads();
    int p = c * 256 + tid;
    float d0 = bdg[p], d1 = bdg[NPTS + p];
    int j = (d1 < d0) ? bjg[NPTS + p] : bjg[p];
    asn[p] = j;
    atomicAdd(&bins[j], 1);
    __syncthreads();
    hist[c * 256 + tid] = bins[tid];
}

// ---------- per-cluster prefix over 256 chunks ----------------------
__global__ __launch_bounds__(256) void scan_chunks(const int* __restrict__ hist,
        int* __restrict__ chunkbase, int* __restrict__ totals) {
    __shared__ int a[256];
    int j = blockIdx.x, c = threadIdx.x;
    a[c] = hist[(size_t)c * 256 + j];
    __syncthreads();
    for (int d = 1; d < 256; d <<= 1) {
        int v = a[c];
        int u = (c >= d) ? a[c - d] : 0;
        __syncthreads();
        a[c] = v + u;
        __syncthreads();
    }
    chunkbase[(size_t)c * 256 + j] = (c == 0) ? 0 : a[c - 1];
    if (c == 255) totals[j] = a[255];
}

// ---------- scatter: parallel cbase scan + stable rank --------------
__global__ __launch_bounds__(256) void scatter_v5(const int* __restrict__ asn,
        const int* __restrict__ chunkbase, const int* __restrict__ totals,
        int* __restrict__ perm) {
    __shared__ int cb[256];
    __shared__ int al[256];
    int c = blockIdx.x, tid = threadIdx.x;
    cb[tid] = totals[tid];
    al[tid] = asn[c * 256 + tid];
    __syncthreads();
    for (int d = 1; d < 256; d <<= 1) {
        int v = cb[tid];
        int u = (tid >= d) ? cb[tid - d] : 0;
        __syncthreads();
        cb[tid] = v + u;
        __syncthreads();
    }
    int my = al[tid];
    int base = (my == 0) ? 0 : cb[my - 1];
    int r = 0;
    for (int i = 0; i < tid; i++) r += (al[i] == my) ? 1 : 0;
    perm[base + chunkbase[(size_t)c * 256 + my] + r] = c * 256 + tid;
}

// ---------- ordered sum + update + cc (parallel cbase scan) ---------
#define STILE 128
__global__ __launch_bounds__(256) void sumk_v4(const float* __restrict__ pts,
        const int* __restrict__ perm, const int* __restrict__ totals,
        float* __restrict__ cent, float* __restrict__ cc) {
    __shared__ int cb[256];
    __shared__ float buf[2][STILE][32];
    int j = blockIdx.x, tid = threadIdx.x;
    cb[tid] = totals[tid];
    __syncthreads();
    for (int d = 1; d < 256; d <<= 1) {
        int v = cb[tid];
        int u = (tid >= d) ? cb[tid - d] : 0;
        __syncthreads();
        cb[tid] = v + u;
        __syncthreads();
    }
    int base = (j == 0) ? 0 : cb[j - 1];
    int n = totals[j];
    int t = tid & 31, r0 = tid >> 5;
    for (int r = r0; r < STILE; r += 8) {
        if (r < n) buf[0][r][t] = pts[(size_t)perm[base + r] * 32 + t];
    }
    __syncthreads();
    float s = 0.f;
    int b = 0;
    for (int i0 = 0; i0 < n; i0 += STILE, b ^= 1) {
        int nx = i0 + STILE;
        if (nx < n) {
            for (int r = r0; r < STILE; r += 8) {
                int g = nx + r;
                if (g < n) buf[b ^ 1][r][t] = pts[(size_t)perm[base + g] * 32 + t];
            }
        }
        if (tid < 32) {
            int m = n - i0; if (m > STILE) m = STILE;
            int i = 0;
            for (; i + 4 <= m; i += 4) {
                s = fadd(s, buf[b][i][tid]);
                s = fadd(s, buf[b][i + 1][tid]);
                s = fadd(s, buf[b][i + 2][tid]);
                s = fadd(s, buf[b][i + 3][tid]);
            }
            for (; i < m; i++) s = fadd(s, buf[b][i][tid]);
        }
        __syncthreads();
    }
    if (tid < 32) {
        float v;
        if (n > 0) {
            v = __fdiv_rn(s, (float)n);
            cent[(size_t)j * 32 + tid] = v;
        } else {
            v = cent[(size_t)j * 32 + tid];
        }
        float e = fmul(v, v);
        e = fadd(e, __shfl_xor(e, 16));
        e = fadd(e, __shfl_xor(e, 8));
        e = fadd(e, __shfl_xor(e, 4));
        e = fadd(e, __shfl_xor(e, 2));
        e = fadd(e, __shfl_xor(e, 1));
        if (tid == 0) cc[j] = e;
    }
}

// ---------- key assign + L1: conflict-free + packed -----------------
__global__ __launch_bounds__(256) void kdist4p(const float* __restrict__ pts,
        const float* __restrict__ cent, const float* __restrict__ cc,
        float* __restrict__ kd) {
    __shared__ float sc[256 * 36];
    __shared__ float scc[256];
    int tid = threadIdx.x, c = blockIdx.x;
    {
        const float4* c4 = (const float4*)cent;
        for (int i = tid; i < 256 * 8; i += 256) {
            int row = i >> 3, t = i & 7;
            ((float4*)(sc + row * 36))[t] = c4[i];
        }
    }
    scc[tid] = cc[tid];
    __syncthreads();
    int pg = tid >> 2, quarter = tid & 3;
    int pb = c * 256 + pg * 4;
    v2f xp2[2][32];
    float xp[4];
    #pragma unroll
    for (int i = 0; i < 4; i++) {
        const float4* pp = (const float4*)(pts + (size_t)(pb + i) * 32);
        float e[32];
        #pragma unroll
        for (int t = 0; t < 8; t++) {
            float4 f = pp[t];
            xp2[i >> 1][4*t+0][i & 1] = f.x;
            xp2[i >> 1][4*t+1][i & 1] = f.y;
            xp2[i >> 1][4*t+2][i & 1] = f.z;
            xp2[i >> 1][4*t+3][i & 1] = f.w;
            e[4*t+0] = fmul(f.x, f.x);
            e[4*t+1] = fmul(f.y, f.y);
            e[4*t+2] = fmul(f.z, f.z);
            e[4*t+3] = fmul(f.w, f.w);
        }
        xp[i] = sum32_np(e);
    }
    float bd[4] = {3.4e38f, 3.4e38f, 3.4e38f, 3.4e38f};
    int bj[4] = {0x7fffffff, 0x7fffffff, 0x7fffffff, 0x7fffffff};
    for (int jj = 0; jj < 64; jj++) {
        int j = (jj << 2) | quarter;
        const float4* cj = (const float4*)(sc + j * 36);
        float w[32];
        #pragma unroll
        for (int t = 0; t < 8; t++) {
            float4 f = cj[t];
            w[4*t] = f.x; w[4*t+1] = f.y; w[4*t+2] = f.z; w[4*t+3] = f.w;
        }
        float sj = scc[j];
        v2f g0 = {0.f, 0.f}, g1 = {0.f, 0.f};
        #pragma unroll
        for (int t = 0; t < 32; t++) {
            v2f wv = {w[t], w[t]};
            g0 = __builtin_elementwise_fma(xp2[0][t], wv, g0);
            g1 = __builtin_elementwise_fma(xp2[1][t], wv, g1);
        }
        #pragma unroll
        for (int i = 0; i < 4; i++) {
            float g = (i < 2) ? g0[i & 1] : g1[i & 1];
            float d = fadd(fsub(xp[i], fmul(2.f, g)), sj);
            if (d < bd[i]) { bd[i] = d; bj[i] = j; }
        }
    }
    // lexicographic (d, j) combine across the 4 quarters
    #pragma unroll
    for (int i = 0; i < 4; i++) {
        float ob; int oj;
        ob = __shfl_xor(bd[i], 1); oj = __shfl_xor(bj[i], 1);
        if (ob < bd[i] || (ob == bd[i] && oj < bj[i])) { bd[i] = ob; bj[i] = oj; }
        ob = __shfl_xor(bd[i], 2); oj = __shfl_xor(bj[i], 2);
        if (ob < bd[i] || (ob == bd[i] && oj < bj[i])) { bd[i] = ob; bj[i] = oj; }
    }
    if (quarter == 0) {
        #pragma unroll
        for (int i = 0; i < 4; i++) {
            const float* cb = &sc[bj[i] * 36];
            float e[32];
            #pragma unroll
            for (int t = 0; t < 32; t++) {
                float xv = xp2[i >> 1][t][i & 1];
                e[t] = fabsf(fsub(cb[t], xv));
            }
            kd[pb + i] = sum32_np(e);
        }
    }
}

// ---------- top-256 via bit-descent select (exact stable set) -------
__global__ __launch_bounds__(256) void topk_v3(const float* __restrict__ kd,
        const float* __restrict__ k_t, const float* __restrict__ v_t,
        float* __restrict__ ksel, float* __restrict__ vsel) {
    __shared__ int wsum[4];
    __shared__ int sc1[256];
    __shared__ int out_src[256];
    int bh = blockIdx.x, tid = threadIdx.x;
    int wave = tid >> 6, lane = tid & 63;
    unsigned uv[16];
    {
        const unsigned* kdu = (const unsigned*)(kd + (size_t)bh * 4096);
        #pragma unroll
        for (int q = 0; q < 16; q++) uv[q] = kdu[tid * 16 + q];
    }
    unsigned T = 0u;
    for (int bit = 31; bit >= 0; bit--) {
        unsigned cand = T | (1u << bit);
        int c = 0;
        #pragma unroll
        for (int q = 0; q < 16; q++) c += (uv[q] >= cand) ? 1 : 0;
        c += __shfl_xor(c, 32); c += __shfl_xor(c, 16); c += __shfl_xor(c, 8);
        c += __shfl_xor(c, 4);  c += __shfl_xor(c, 2);  c += __shfl_xor(c, 1);
        if (lane == 0) wsum[wave] = c;
        __syncthreads();
        int tot = wsum[0] + wsum[1] + wsum[2] + wsum[3];
        __syncthreads();
        if (tot >= 256) T = cand;
    }
    int r;
    {
        int c = 0;
        #pragma unroll
        for (int q = 0; q < 16; q++) c += (uv[q] > T) ? 1 : 0;
        c += __shfl_xor(c, 32); c += __shfl_xor(c, 16); c += __shfl_xor(c, 8);
        c += __shfl_xor(c, 4);  c += __shfl_xor(c, 2);  c += __shfl_xor(c, 1);
        if (lane == 0) wsum[wave] = c;
        __syncthreads();
        r = 256 - (wsum[0] + wsum[1] + wsum[2] + wsum[3]);
        __syncthreads();
    }
    int ec = 0;
    #pragma unroll
    for (int q = 0; q < 16; q++) ec += (uv[q] == T) ? 1 : 0;
    sc1[tid] = ec;
    __syncthreads();
    for (int d = 1; d < 256; d <<= 1) {
        int t0 = sc1[tid];
        int u0 = (tid >= d) ? sc1[tid - d] : 0;
        __syncthreads();
        sc1[tid] = t0 + u0;
        __syncthreads();
    }
    int erank = (tid == 0) ? 0 : sc1[tid - 1];
    __syncthreads();
    bool incl[16];
    int ic = 0;
    #pragma unroll
    for (int q = 0; q < 16; q++) {
        unsigned u = uv[q];
        bool inc;
        if (u > T) inc = true;
        else if (u == T) { inc = (erank < r); erank++; }
        else inc = false;
        incl[q] = inc;
        ic += inc ? 1 : 0;
    }
    sc1[tid] = ic;
    __syncthreads();
    for (int d = 1; d < 256; d <<= 1) {
        int t0 = sc1[tid];
        int u0 = (tid >= d) ? sc1[tid - d] : 0;
        __syncthreads();
        sc1[tid] = t0 + u0;
        __syncthreads();
    }
    int pos = (tid == 0) ? 0 : sc1[tid - 1];
    int base_i = tid * 16;
    #pragma unroll
    for (int q = 0; q < 16; q++) {
        if (incl[q]) out_src[pos++] = base_i + q;
    }
    __syncthreads();
    for (int e = tid; e < 256 * 32; e += 256) {
        int jj = e >> 5, t = e & 31;
        int src = out_src[jj];
        ksel[(size_t)bh * 8192 + e] = k_t[((size_t)bh * 4096 + src) * 32 + t];
        vsel[(size_t)bh * 8192 + e] = v_t[((size_t)bh * 4096 + src) * 32 + t];
    }
}

// ---------- attention v4: 8-thread groups (4 slices x 2 dh), Q=4 ----
#define HP4 2052
__global__ __launch_bounds__(256, 2) void attn_v4(const float* __restrict__ q_t,
        const float* __restrict__ ksel, const float* __restrict__ vsel,
        float* __restrict__ out) {
    __shared__ float sk[4 * HP4];
    __shared__ float sv[4 * HP4];
    int bh = blockIdx.y, tid = threadIdx.x;
    {
        const float4* gk = (const float4*)(ksel + (size_t)bh * 8192);
        const float4* gv = (const float4*)(vsel + (size_t)bh * 8192);
        for (int i = tid; i < 2048; i += 256) {
            int s = i >> 9, idx = i & 511;
            ((float4*)(sk + s * HP4))[idx] = gk[i];
            ((float4*)(sv + s * HP4))[idx] = gv[i];
        }
    }
    __syncthreads();
    int grp = tid >> 3;              // 32 groups of 8 lanes
    int dh = tid & 1;                // dim half
    int slice = (tid >> 1) & 3;      // key quarter
    int p0 = bh * 4096 + blockIdx.x * 128 + grp * 4;
    float q[4][16];
    #pragma unroll
    for (int i = 0; i < 4; i++) {
        const float4* qp = (const float4*)(q_t + (size_t)(p0 + i) * 32 + dh * 16);
        #pragma unroll
        for (int t = 0; t < 4; t++) {
            float4 f = qp[t];
            q[i][4*t] = f.x; q[i][4*t+1] = f.y; q[i][4*t+2] = f.z; q[i][4*t+3] = f.w;
        }
    }
    float o[4][16];
    #pragma unroll
    for (int i = 0; i < 4; i++)
        #pragma unroll
        for (int t = 0; t < 16; t++) o[i][t] = 0.f;
    float ls[4] = {0.f, 0.f, 0.f, 0.f};
    const float* kb = sk + slice * HP4 + dh * 16;
    const float* vb = sv + slice * HP4 + dh * 16;
    for (int j = 0; j < 64; j++) {
        float kf[16];
        #pragma unroll
        for (int t = 0; t < 4; t++) {
            float4 f = *(const float4*)(kb + j * 32 + t * 4);
            kf[4*t] = f.x; kf[4*t+1] = f.y; kf[4*t+2] = f.z; kf[4*t+3] = f.w;
        }
        float ps[4];
        #pragma unroll
        for (int i = 0; i < 4; i++) {
            float a = 0.f, b2 = 0.f, c2 = 0.f, d2 = 0.f;
            #pragma unroll
            for (int t = 0; t < 4; t++) {
                a  += q[i][4*t]   * kf[4*t];
                b2 += q[i][4*t+1] * kf[4*t+1];
                c2 += q[i][4*t+2] * kf[4*t+2];
                d2 += q[i][4*t+3] * kf[4*t+3];
            }
            ps[i] = (a + b2) + (c2 + d2);
        }
        #pragma unroll
        for (int i = 0; i < 4; i++) ps[i] += __shfl_xor(ps[i], 1);  // dh combine
        float w[4];
        #pragma unroll
        for (int i = 0; i < 4; i++) {
            w[i] = __expf(ps[i] - 1.0f);
            ls[i] += w[i];
        }
        float vf[16];
        #pragma unroll
        for (int t = 0; t < 4; t++) {
            float4 f = *(const float4*)(vb + j * 32 + t * 4);
            vf[4*t] = f.x; vf[4*t+1] = f.y; vf[4*t+2] = f.z; vf[4*t+3] = f.w;
        }
        #pragma unroll
        for (int i = 0; i < 4; i++)
            #pragma unroll
            for (int t = 0; t < 16; t++) o[i][t] += w[i] * vf[t];
    }
    // combine the 4 key slices (tree: (s0+s1)+(s2+s3))
    #pragma unroll
    for (int i = 0; i < 4; i++) {
        #pragma unroll
        for (int t = 0; t < 16; t++) {
            o[i][t] += __shfl_xor(o[i][t], 2);
            o[i][t] += __shfl_xor(o[i][t], 4);
        }
        ls[i] += __shfl_xor(ls[i], 2);
        ls[i] += __shfl_xor(ls[i], 4);
    }
    if (slice == 0) {
        #pragma unroll
        for (int i = 0; i < 4; i++) {
            float inv = 1.f / ls[i];
            float4* op = (float4*)(out + (size_t)(p0 + i) * 32 + dh * 16);
            #pragma unroll
            for (int t = 0; t < 4; t++)
                op[t] = make_float4(o[i][4*t]*inv, o[i][4*t+1]*inv,
                                    o[i][4*t+2]*inv, o[i][4*t+3]*inv);
        }
    }
}

// ---------- unfold (bh,L,32) -> (b,256,L) ---------------------------
__global__ __launch_bounds__(256) void unfold_kernel(const float* __restrict__ att,
        float* __restrict__ Fo) {
    __shared__ float tbuf[32][65];
    int bh = blockIdx.y, l0 = blockIdx.x * 64;
    int b = bh >> 3, h = bh & 7;
    int tid = threadIdx.x;
    #pragma unroll
    for (int r = 0; r < 8; r++) {
        int e = r * 256 + tid;
        int l = e >> 5, d = e & 31;
        tbuf[d][l] = att[((size_t)bh * 4096 + l0 + l) * 32 + d];
    }
    __syncthreads();
    #pragma unroll
    for (int r = 0; r < 8; r++) {
        int e = r * 256 + tid;
        int d = e >> 6, l = e & 63;
        Fo[((size_t)b * 256 + h * 32 + d) * LSEQ + l0 + l] = tbuf[d][l];
    }
}

// ---------- final LN + scale + residual, LDS-cached (numpy orders) --
__global__ __launch_bounds__(64) void lnres_np(const float* __restrict__ x,
        const float* __restrict__ g, const float* __restrict__ bt,
        const float* __restrict__ gs, const float* __restrict__ qsrc,
        float* __restrict__ y) {
    __shared__ float xl[256 * 64];
    __shared__ float ql[256 * 64];
    int tid = threadIdx.x;
    int gid = blockIdx.x * 64 + tid;
    int b = gid >> 12, l = gid & 4095;
    const float* xb = x + (size_t)b * CDIM * LSEQ + l;
    const float* qb = qsrc + (size_t)b * CDIM * LSEQ + l;
    #pragma unroll 8
    for (int c = 0; c < 256; c++) {
        gld_lds4(xb + (size_t)c * LSEQ, xl + c * 64);
        gld_lds4(qb + (size_t)c * LSEQ, ql + c * 64);
    }
    __syncthreads();
    float s = 0.f;
    #pragma unroll 8
    for (int c = 0; c < 256; c++) s = fadd(s, xl[c * 64 + tid]);
    float mean = __fdiv_rn(s, 256.f);
    float s2 = 0.f;
    #pragma unroll 8
    for (int c = 0; c < 256; c++) {
        float d = fsub(xl[c * 64 + tid], mean);
        s2 = fadd(s2, fmul(d, d));
    }
    float var = __fdiv_rn(s2, 256.f);
    float den = fadd(__fsqrt_rn(var), 1e-6f);
    float scale = gs[0];
    float* yb = y + (size_t)b * CDIM * LSEQ + l;
    #pragma unroll 4
    for (int c = 0; c < 256; c++) {
        float d = fsub(xl[c * 64 + tid], mean);
        float r = fadd(__fdiv_rn(fmul(g[c], d), den), bt[c]);
        yb[(size_t)c * LSEQ] = fadd(fmul(scale, r), ql[c * 64 + tid]);
    }
}

// ==================================================================
extern "C" void kernel_launch(void* const* d_in, const int* in_sizes, int n_in,
                              void* d_out, int out_size, void* d_ws, size_t ws_size,
                              hipStream_t stream) {
    const float* qsrc   = (const float*)d_in[0];
    const float* ctx    = (const float*)d_in[1];
    const float* w_q    = (const float*)d_in[2];
    const float* w_kv   = (const float*)d_in[3];
    const float* w_out  = (const float*)d_in[4];
    const float* g_ctx  = (const float*)d_in[5];
    const float* b_ctx  = (const float*)d_in[6];
    const float* g_q    = (const float*)d_in[7];
    const float* b_q    = (const float*)d_in[8];
    const float* g_out  = (const float*)d_in[9];
    const float* b_out  = (const float*)d_in[10];
    const float* gs     = (const float*)d_in[11];

    char* base = (char*)d_ws;
    const size_t MB = 1024 * 1024;
    float* yln   = (float*)base;               // [0,8) ctx LN; later att
    float* att   = (float*)base;
    float* kvbuf = (float*)(base + 8 * MB);    // [8,24) kv conv; later bdg/bjg; later y32
    float* y32   = (float*)(base + 8 * MB);
    float* bdg   = (float*)(base + 8 * MB);    // 512 KB (2*NPTS floats) during k-means
    int*   bjg   = (int*)  (base + 9 * MB);    // 512 KB during k-means
    float* qbuf  = (float*)(base + 24 * MB);   // [24,32) q conv; later Fo
    float* Fo    = (float*)(base + 24 * MB);
    float* q_t   = (float*)(base + 32 * MB);   // [32,40)
    float* k_t   = (float*)(base + 40 * MB);   // [40,48)
    float* v_t   = (float*)(base + 48 * MB);   // [48,56)
    char* SM = base + 56 * MB;
    float* xx_q      = (float*)(SM + 0);            // 256 KB
    float* cent      = (float*)(SM + 512 * 1024);   // 32 KB
    float* cc        = (float*)(SM + 576 * 1024);   // 1 KB
    int*   totals    = (int*)  (SM + 640 * 1024);   // 1 KB
    int*   asn       = (int*)  (SM + 704 * 1024);   // 256 KB
    int*   hist      = (int*)  (SM + 960 * 1024);   // 256 KB
    int*   chunkbase = (int*)  (SM + 1472 * 1024);  // 256 KB
    int*   perm      = (int*)  (SM + 1984 * 1024);  // 256 KB
    float* kd        = (float*)(SM + 2240 * 1024);  // 256 KB
    float* ksel      = (float*)(SM + 2496 * 1024);  // 512 KB
    float* vsel      = (float*)(SM + 3008 * 1024);  // 512 KB
    float* yln_q     = (float*)(base + 60 * MB);    // [60,68) q LN out

    ln2_np<<<256, 64, 0, stream>>>(ctx, g_ctx, b_ctx, yln,
                                   qsrc, g_q, b_q, yln_q);
    conv_all16<<<dim3(8, 48, 2), 256, 0, stream>>>(w_kv, yln, kvbuf,
                                                   w_q, yln_q, qbuf);
    fold3_np<<<768, 256, 0, stream>>>(kvbuf, qbuf, k_t, v_t, q_t, xx_q, cent, cc);

    for (int it = 0; it < 10; it++) {
        assign_h<<<512, 256, 0, stream>>>(q_t, xx_q, cent, cc, bdg, bjg);
        merge_asn<<<256, 256, 0, stream>>>(bdg, bjg, asn, hist);
        scan_chunks<<<256, 256, 0, stream>>>(hist, chunkbase, totals);
        scatter_v5<<<256, 256, 0, stream>>>(asn, chunkbase, totals, perm);
        sumk_v4<<<256, 256, 0, stream>>>(q_t, perm, totals, cent, cc);
    }

    kdist4p<<<256, 256, 0, stream>>>(k_t, cent, cc, kd);
    topk_v3<<<16, 256, 0, stream>>>(kd, k_t, v_t, ksel, vsel);
    attn_v4<<<dim3(32, 16), 256, 0, stream>>>(q_t, ksel, vsel, att);
    unfold_kernel<<<dim3(64, 16), 256, 0, stream>>>(att, Fo);
    conv_q8<false><<<dim3(4, 32, 2), 256, 0, stream>>>(w_out, Fo, y32);
    lnres_np<<<128, 64, 0, stream>>>(y32, g_out, b_out, gs, qsrc, (float*)d_out);
}

// Round 15
// 792.492 us; speedup vs baseline: 1.9470x; 1.0507x over previous
//
#include <hip/hip_runtime.h>
#include <math.h>

#define CDIM 256
#define LSEQ 4096
#define NBH 16
#define NPTS 65536
#define KC 256

typedef float v2f __attribute__((ext_vector_type(2)));

__device__ __forceinline__ float fadd(float a, float b){ return __fadd_rn(a,b); }
__device__ __forceinline__ float fmul(float a, float b){ return __fmul_rn(a,b); }
__device__ __forceinline__ float fsub(float a, float b){ return __fsub_rn(a,b); }

// async global->LDS, width 4: per-lane global src, wave-uniform LDS base,
// lane i lands at base + i*4 (guide §5 / m03)
__device__ __forceinline__ void gld_lds4(const float* g, float* l){
    __builtin_amdgcn_global_load_lds(
        (const __attribute__((address_space(1))) unsigned int*)g,
        (__attribute__((address_space(3))) unsigned int*)l, 4, 0, 0);
}

// numpy contiguous n=32 float32 sum, AVX-512 npyv path (verified R5)
__device__ __forceinline__ float sum32_np(const float* e){
    float l[16];
    #pragma unroll
    for (int j = 0; j < 16; j++) l[j] = fadd(e[j], e[j + 16]);
    float t3[8];
    #pragma unroll
    for (int j = 0; j < 8; j++) t3[j] = fadd(l[j], l[j + 8]);
    float t6[4];
    #pragma unroll
    for (int j = 0; j < 4; j++) t6[j] = fadd(t3[j], t3[j + 4]);
    return fadd(fadd(t6[0], t6[2]), fadd(t6[1], t6[3]));
}

// ---------- both LayerNorms, LDS-cached (numpy exact per position) --
__global__ __launch_bounds__(64) void ln2_np(
        const float* __restrict__ x0, const float* __restrict__ g0,
        const float* __restrict__ bt0, float* __restrict__ y0,
        const float* __restrict__ x1, const float* __restrict__ g1,
        const float* __restrict__ bt1, float* __restrict__ y1) {
    __shared__ float xl[256 * 64];
    int tid = threadIdx.x;
    int gid = blockIdx.x * 64 + tid;
    int which = gid >> 13;
    int r = gid & 8191;
    int b = r >> 12, l = r & 4095;
    const float* x  = which ? x1 : x0;
    const float* g  = which ? g1 : g0;
    const float* bt = which ? bt1 : bt0;
    float* y        = which ? y1 : y0;
    const float* xb = x + (size_t)b * CDIM * LSEQ + l;
    #pragma unroll 8
    for (int c = 0; c < 256; c++)
        gld_lds4(xb + (size_t)c * LSEQ, xl + c * 64);
    __syncthreads();
    float s = 0.f;
    #pragma unroll 8
    for (int c = 0; c < 256; c++) s = fadd(s, xl[c * 64 + tid]);
    float mean = __fdiv_rn(s, 256.f);
    float s2 = 0.f;
    #pragma unroll 8
    for (int c = 0; c < 256; c++) {
        float d = fsub(xl[c * 64 + tid], mean);
        s2 = fadd(s2, fmul(d, d));
    }
    float var = __fdiv_rn(s2, 256.f);
    float den = fadd(__fsqrt_rn(var), 1e-6f);
    float* yb = y + (size_t)b * CDIM * LSEQ + l;
    #pragma unroll 4
    for (int c = 0; c < 256; c++) {
        float d = fsub(xl[c * 64 + tid], mean);
        yb[(size_t)c * LSEQ] = fadd(__fdiv_rn(fmul(g[c], d), den), bt[c]);
    }
}

// ---------- fused conv (kv + q), COT=16, NL=2, packed f32 -----------
__global__ __launch_bounds__(256) void conv_all16(
        const float* __restrict__ Wkv, const float* __restrict__ Xkv,
        float* __restrict__ Ykv,
        const float* __restrict__ Wq, const float* __restrict__ Xq,
        float* __restrict__ Yq) {
    int tid = threadIdx.x;
    int l0 = blockIdx.x * 512 + tid * 2;
    bool qpath = blockIdx.y >= 32;
    int yb = qpath ? (blockIdx.y - 32) : blockIdx.y;
    int o0 = yb * 16;
    int b = blockIdx.z;
    const float4* w4 = (const float4*)((qpath ? Wq : Wkv) + (size_t)o0 * CDIM);
    const float* X = qpath ? Xq : Xkv;
    const float* xb = X + (size_t)b * CDIM * LSEQ;
    v2f acc[16];
    #pragma unroll
    for (int oo = 0; oo < 16; oo++) acc[oo] = (v2f){0.f, 0.f};
    bool sop = qpath || (blockIdx.y < 16);
    if (sop) {
        for (int c = 0; c < 256; c += 4) {
            v2f x0q = *(const v2f*)(xb + (size_t)(c + 0) * LSEQ + l0);
            v2f x1q = *(const v2f*)(xb + (size_t)(c + 1) * LSEQ + l0);
            v2f x2q = *(const v2f*)(xb + (size_t)(c + 2) * LSEQ + l0);
            v2f x3q = *(const v2f*)(xb + (size_t)(c + 3) * LSEQ + l0);
            #pragma unroll
            for (int oo = 0; oo < 16; oo++) {
                float4 w = w4[(oo * 256 + c) >> 2];
                acc[oo] = acc[oo] + (v2f){w.x, w.x} * x0q;
                acc[oo] = acc[oo] + (v2f){w.y, w.y} * x1q;
                acc[oo] = acc[oo] + (v2f){w.z, w.z} * x2q;
                acc[oo] = acc[oo] + (v2f){w.w, w.w} * x3q;
            }
        }
    } else {
        for (int c = 0; c < 256; c += 4) {
            v2f x0q = *(const v2f*)(xb + (size_t)(c + 0) * LSEQ + l0);
            v2f x1q = *(const v2f*)(xb + (size_t)(c + 1) * LSEQ + l0);
            v2f x2q = *(const v2f*)(xb + (size_t)(c + 2) * LSEQ + l0);
            v2f x3q = *(const v2f*)(xb + (size_t)(c + 3) * LSEQ + l0);
            #pragma unroll
            for (int oo = 0; oo < 16; oo++) {
                float4 w = w4[(oo * 256 + c) >> 2];
                acc[oo] = __builtin_elementwise_fma((v2f){w.x, w.x}, x0q, acc[oo]);
                acc[oo] = __builtin_elementwise_fma((v2f){w.y, w.y}, x1q, acc[oo]);
                acc[oo] = __builtin_elementwise_fma((v2f){w.z, w.z}, x2q, acc[oo]);
                acc[oo] = __builtin_elementwise_fma((v2f){w.w, w.w}, x3q, acc[oo]);
            }
        }
    }
    float* Y = qpath ? Yq : Ykv;
    int rows = qpath ? 256 : 512;
    #pragma unroll
    for (int oo = 0; oo < 16; oo++)
        *(v2f*)(Y + ((size_t)b * rows + o0 + oo) * LSEQ + l0) = acc[oo];
}

// ---------- conv 256-row: COT=8, NL=4, LDS, packed f32 --------------
template<bool EXACT>
__global__ __launch_bounds__(256) void conv_q8(const float* __restrict__ W,
        const float* __restrict__ X, float* __restrict__ Y) {
    __shared__ float ws[8 * 256];
    int tid = threadIdx.x;
    int l0 = blockIdx.x * 1024 + tid * 4;
    int o0 = blockIdx.y * 8;
    int b = blockIdx.z;
    {
        const float4* wb4 = (const float4*)(W + (size_t)o0 * CDIM);
        float4* ws4s = (float4*)ws;
        for (int i = tid; i < 8 * 64; i += 256) ws4s[i] = wb4[i];
    }
    __syncthreads();
    const float* xb = X + (size_t)b * CDIM * LSEQ;
    v2f acc[8][2];
    #pragma unroll
    for (int oo = 0; oo < 8; oo++) {
        acc[oo][0] = (v2f){0.f, 0.f};
        acc[oo][1] = (v2f){0.f, 0.f};
    }
    const float4* ws4 = (const float4*)ws;
    for (int c = 0; c < 256; c += 4) {
        float4 x0q = *(const float4*)(xb + (size_t)(c + 0) * LSEQ + l0);
        float4 x1q = *(const float4*)(xb + (size_t)(c + 1) * LSEQ + l0);
        float4 x2q = *(const float4*)(xb + (size_t)(c + 2) * LSEQ + l0);
        float4 x3q = *(const float4*)(xb + (size_t)(c + 3) * LSEQ + l0);
        v2f x0a = {x0q.x, x0q.y}, x0b = {x0q.z, x0q.w};
        v2f x1a = {x1q.x, x1q.y}, x1b = {x1q.z, x1q.w};
        v2f x2a = {x2q.x, x2q.y}, x2b = {x2q.z, x2q.w};
        v2f x3a = {x3q.x, x3q.y}, x3b = {x3q.z, x3q.w};
        #pragma unroll
        for (int oo = 0; oo < 8; oo++) {
            float4 w = ws4[(oo * 256 + c) >> 2];
            if (EXACT) {
                acc[oo][0] = acc[oo][0] + (v2f){w.x, w.x} * x0a;
                acc[oo][1] = acc[oo][1] + (v2f){w.x, w.x} * x0b;
                acc[oo][0] = acc[oo][0] + (v2f){w.y, w.y} * x1a;
                acc[oo][1] = acc[oo][1] + (v2f){w.y, w.y} * x1b;
                acc[oo][0] = acc[oo][0] + (v2f){w.z, w.z} * x2a;
                acc[oo][1] = acc[oo][1] + (v2f){w.z, w.z} * x2b;
                acc[oo][0] = acc[oo][0] + (v2f){w.w, w.w} * x3a;
                acc[oo][1] = acc[oo][1] + (v2f){w.w, w.w} * x3b;
            } else {
                acc[oo][0] = __builtin_elementwise_fma((v2f){w.x, w.x}, x0a, acc[oo][0]);
                acc[oo][1] = __builtin_elementwise_fma((v2f){w.x, w.x}, x0b, acc[oo][1]);
                acc[oo][0] = __builtin_elementwise_fma((v2f){w.y, w.y}, x1a, acc[oo][0]);
                acc[oo][1] = __builtin_elementwise_fma((v2f){w.y, w.y}, x1b, acc[oo][1]);
                acc[oo][0] = __builtin_elementwise_fma((v2f){w.z, w.z}, x2a, acc[oo][0]);
                acc[oo][1] = __builtin_elementwise_fma((v2f){w.z, w.z}, x2b, acc[oo][1]);
                acc[oo][0] = __builtin_elementwise_fma((v2f){w.w, w.w}, x3a, acc[oo][0]);
                acc[oo][1] = __builtin_elementwise_fma((v2f){w.w, w.w}, x3b, acc[oo][1]);
            }
        }
    }
    #pragma unroll
    for (int oo = 0; oo < 8; oo++)
        *(float4*)(Y + ((size_t)b * 256 + o0 + oo) * LSEQ + l0) =
            make_float4(acc[oo][0][0], acc[oo][0][1], acc[oo][1][0], acc[oo][1][1]);
}

// ---------- fold x3 (k norm, v plain, q norm+xx+cent/cc) ------------
__device__ __forceinline__ void fold_body(const float* __restrict__ src,
        int srcRows, int row0, int donorm, float* __restrict__ dst,
        float* __restrict__ xxout, float* __restrict__ centout,
        float* __restrict__ ccout, int p) {
    int bh = p >> 12, l = p & 4095;
    int b = bh >> 3, h = bh & 7;
    const float* sp = src + ((size_t)b * srcRows + row0 + h * 32) * LSEQ + l;
    float x[32];
    #pragma unroll
    for (int t = 0; t < 32; t++) x[t] = sp[(size_t)t * LSEQ];
    float4* dp4 = (float4*)(dst + (size_t)p * 32);
    if (donorm) {
        float ss = 0.f;
        #pragma unroll
        for (int t = 0; t < 32; t++) ss = fadd(ss, fmul(x[t], x[t]));
        float n = __fsqrt_rn(ss);
        float den = fmaxf(n, 1e-12f);
        #pragma unroll
        for (int t = 0; t < 32; t++) x[t] = __fdiv_rn(x[t], den);
    }
    #pragma unroll
    for (int t = 0; t < 8; t++)
        dp4[t] = make_float4(x[4*t], x[4*t+1], x[4*t+2], x[4*t+3]);
    if (xxout) {
        float e[32];
        #pragma unroll
        for (int t = 0; t < 32; t++) e[t] = fmul(x[t], x[t]);
        float xv = sum32_np(e);
        xxout[p] = xv;
        if (centout && p < KC) {
            float4* cp4 = (float4*)(centout + (size_t)p * 32);
            #pragma unroll
            for (int t = 0; t < 8; t++)
                cp4[t] = make_float4(x[4*t], x[4*t+1], x[4*t+2], x[4*t+3]);
            ccout[p] = xv;
        }
    }
}

__global__ __launch_bounds__(256) void fold3_np(const float* __restrict__ kvbuf,
        const float* __restrict__ qbuf, float* __restrict__ k_t,
        float* __restrict__ v_t, float* __restrict__ q_t,
        float* __restrict__ xx, float* __restrict__ cent, float* __restrict__ cc) {
    int blk = blockIdx.x, tid = threadIdx.x;
    if (blk < 256) {
        fold_body(kvbuf, 512, 0, 1, k_t, nullptr, nullptr, nullptr, blk * 256 + tid);
    } else if (blk < 512) {
        fold_body(kvbuf, 512, 256, 0, v_t, nullptr, nullptr, nullptr, (blk - 256) * 256 + tid);
    } else {
        fold_body(qbuf, 256, 0, 1, q_t, xx, cent, cc, (blk - 512) * 256 + tid);
    }
}

// ---------- fused assign: both halves + merge in ONE block ----------
// Block = chunk, 512 threads: tid<256 runs half0's assign_h body
// verbatim (own 128-centroid conflict-free stage, 4 pts/quarter,
// interleaved j, lex (d,j) combine), tid>=256 runs half1. Per-point
// (bd,bj) staged in LDS; after __syncthreads, merge_asn's exact rule
// (d1<d0 ? half1 : half0; tie -> half0 = lower j) picks asn, builds
// bins/hist identically. Removes 10 merge launches + bdg/bjg global
// round-trip. 8 waves/block = 2 waves/SIMD (as before).
__global__ __launch_bounds__(512) void assign_full(const float* __restrict__ pts,
        const float* __restrict__ xx, const float* __restrict__ cent,
        const float* __restrict__ cc, int* __restrict__ asn, int* __restrict__ hist) {
    __shared__ float sc[2][128 * 36];
    __shared__ float scc[2][128];
    __shared__ float sbd[2][256];
    __shared__ int   sbj[2][256];
    __shared__ int   bins[256];
    int tid512 = threadIdx.x;
    int h = tid512 >> 8;             // half
    int tid = tid512 & 255;          // lane within half-group
    int c = blockIdx.x;
    {
        const float4* c4 = (const float4*)(cent + (size_t)h * 128 * 32);
        for (int i = tid; i < 128 * 8; i += 256) {
            int row = i >> 3, t = i & 7;
            ((float4*)(sc[h] + row * 36))[t] = c4[i];
        }
    }
    if (tid < 128) scc[h][tid] = cc[h * 128 + tid];
    if (h == 0) bins[tid] = 0;
    __syncthreads();
    int pg = tid >> 2, quarter = tid & 3;
    int pb = c * 256 + pg * 4;
    v2f xp2[2][32];
    float xp[4];
    #pragma unroll
    for (int i = 0; i < 4; i++) {
        const float4* pp = (const float4*)(pts + (size_t)(pb + i) * 32);
        #pragma unroll
        for (int t = 0; t < 8; t++) {
            float4 f = pp[t];
            xp2[i >> 1][4*t+0][i & 1] = f.x;
            xp2[i >> 1][4*t+1][i & 1] = f.y;
            xp2[i >> 1][4*t+2][i & 1] = f.z;
            xp2[i >> 1][4*t+3][i & 1] = f.w;
        }
        xp[i] = xx[pb + i];
    }
    float bd[4] = {3.4e38f, 3.4e38f, 3.4e38f, 3.4e38f};
    int bj[4] = {0x7fffffff, 0x7fffffff, 0x7fffffff, 0x7fffffff};
    for (int jj = 0; jj < 32; jj++) {
        int j = (jj << 2) | quarter;
        const float4* cj = (const float4*)(sc[h] + j * 36);
        float w[32];
        #pragma unroll
        for (int t = 0; t < 8; t++) {
            float4 f = cj[t];
            w[4*t] = f.x; w[4*t+1] = f.y; w[4*t+2] = f.z; w[4*t+3] = f.w;
        }
        float sj = scc[h][j];
        int jg = h * 128 + j;
        v2f g0 = {0.f, 0.f}, g1 = {0.f, 0.f};
        #pragma unroll
        for (int t = 0; t < 32; t++) {
            v2f wv = {w[t], w[t]};
            g0 = __builtin_elementwise_fma(xp2[0][t], wv, g0);
            g1 = __builtin_elementwise_fma(xp2[1][t], wv, g1);
        }
        #pragma unroll
        for (int i = 0; i < 4; i++) {
            float g = (i < 2) ? g0[i & 1] : g1[i & 1];
            float d = fadd(fsub(xp[i], fmul(2.f, g)), sj);
            if (d < bd[i]) { bd[i] = d; bj[i] = jg; }
        }
    }
    // lexicographic (d, j) combine across the 4 quarters
    #pragma unroll
    for (int i = 0; i < 4; i++) {
        float ob; int oj;
        ob = __shfl_xor(bd[i], 1); oj = __shfl_xor(bj[i], 1);
        if (ob < bd[i] || (ob == bd[i] && oj < bj[i])) { bd[i] = ob; bj[i] = oj; }
        ob = __shfl_xor(bd[i], 2); oj = __shfl_xor(bj[i], 2);
        if (ob < bd[i] || (ob == bd[i] && oj < bj[i])) { bd[i] = ob; bj[i] = oj; }
    }
    if (quarter == 0) {
        #pragma unroll
        for (int i = 0; i < 4; i++) {
            sbd[h][pg * 4 + i] = bd[i];
            sbj[h][pg * 4 + i] = bj[i];
        }
    }
    __syncthreads();
    // merge (exact merge_asn rule), threads 0-255 only
    if (h == 0) {
        float d0 = sbd[0][tid], d1 = sbd[1][tid];
        int j = (d1 < d0) ? sbj[1][tid] : sbj[0][tid];
        asn[c * 256 + tid] = j;
        atomicAdd(&bins[j], 1);
    }
    __syncthreads();
    if (h == 0) hist[c * 256 + tid] = bins[tid];
}

// ---------- per-cluster prefix over 256 chunks ----------------------
__global__ __launch_bounds__(256) void scan_chunks(const int* __restrict__ hist,
        int* __restrict__ chunkbase, int* __restrict__ totals) {
    __shared__ int a[256];
    int j = blockIdx.x, c = threadIdx.x;
    a[c] = hist[(size_t)c * 256 + j];
    __syncthreads();
    for (int d = 1; d < 256; d <<= 1) {
        int v = a[c];
        int u = (c >= d) ? a[c - d] : 0;
        __syncthreads();
        a[c] = v + u;
        __syncthreads();
    }
    chunkbase[(size_t)c * 256 + j] = (c == 0) ? 0 : a[c - 1];
    if (c == 255) totals[j] = a[255];
}

// ---------- scatter: parallel cbase scan + stable rank --------------
__global__ __launch_bounds__(256) void scatter_v5(const int* __restrict__ asn,
        const int* __restrict__ chunkbase, const int* __restrict__ totals,
        int* __restrict__ perm) {
    __shared__ int cb[256];
    __shared__ int al[256];
    int c = blockIdx.x, tid = threadIdx.x;
    cb[tid] = totals[tid];
    al[tid] = asn[c * 256 + tid];
    __syncthreads();
    for (int d = 1; d < 256; d <<= 1) {
        int v = cb[tid];
        int u = (tid >= d) ? cb[tid - d] : 0;
        __syncthreads();
        cb[tid] = v + u;
        __syncthreads();
    }
    int my = al[tid];
    int base = (my == 0) ? 0 : cb[my - 1];
    int r = 0;
    for (int i = 0; i < tid; i++) r += (al[i] == my) ? 1 : 0;
    perm[base + chunkbase[(size_t)c * 256 + my] + r] = c * 256 + tid;
}

// ---------- ordered sum + update + cc (parallel cbase scan) ---------
#define STILE 128
__global__ __launch_bounds__(256) void sumk_v4(const float* __restrict__ pts,
        const int* __restrict__ perm, const int* __restrict__ totals,
        float* __restrict__ cent, float* __restrict__ cc) {
    __shared__ int cb[256];
    __shared__ float buf[2][STILE][32];
    int j = blockIdx.x, tid = threadIdx.x;
    cb[tid] = totals[tid];
    __syncthreads();
    for (int d = 1; d < 256; d <<= 1) {
        int v = cb[tid];
        int u = (tid >= d) ? cb[tid - d] : 0;
        __syncthreads();
        cb[tid] = v + u;
        __syncthreads();
    }
    int base = (j == 0) ? 0 : cb[j - 1];
    int n = totals[j];
    int t = tid & 31, r0 = tid >> 5;
    for (int r = r0; r < STILE; r += 8) {
        if (r < n) buf[0][r][t] = pts[(size_t)perm[base + r] * 32 + t];
    }
    __syncthreads();
    float s = 0.f;
    int b = 0;
    for (int i0 = 0; i0 < n; i0 += STILE, b ^= 1) {
        int nx = i0 + STILE;
        if (nx < n) {
            for (int r = r0; r < STILE; r += 8) {
                int g = nx + r;
                if (g < n) buf[b ^ 1][r][t] = pts[(size_t)perm[base + g] * 32 + t];
            }
        }
        if (tid < 32) {
            int m = n - i0; if (m > STILE) m = STILE;
            int i = 0;
            for (; i + 4 <= m; i += 4) {
                s = fadd(s, buf[b][i][tid]);
                s = fadd(s, buf[b][i + 1][tid]);
                s = fadd(s, buf[b][i + 2][tid]);
                s = fadd(s, buf[b][i + 3][tid]);
            }
            for (; i < m; i++) s = fadd(s, buf[b][i][tid]);
        }
        __syncthreads();
    }
    if (tid < 32) {
        float v;
        if (n > 0) {
            v = __fdiv_rn(s, (float)n);
            cent[(size_t)j * 32 + tid] = v;
        } else {
            v = cent[(size_t)j * 32 + tid];
        }
        float e = fmul(v, v);
        e = fadd(e, __shfl_xor(e, 16));
        e = fadd(e, __shfl_xor(e, 8));
        e = fadd(e, __shfl_xor(e, 4));
        e = fadd(e, __shfl_xor(e, 2));
        e = fadd(e, __shfl_xor(e, 1));
        if (tid == 0) cc[j] = e;
    }
}

// ---------- key assign + L1: conflict-free + packed -----------------
__global__ __launch_bounds__(256) void kdist4p(const float* __restrict__ pts,
        const float* __restrict__ cent, const float* __restrict__ cc,
        float* __restrict__ kd) {
    __shared__ float sc[256 * 36];
    __shared__ float scc[256];
    int tid = threadIdx.x, c = blockIdx.x;
    {
        const float4* c4 = (const float4*)cent;
        for (int i = tid; i < 256 * 8; i += 256) {
            int row = i >> 3, t = i & 7;
            ((float4*)(sc + row * 36))[t] = c4[i];
        }
    }
    scc[tid] = cc[tid];
    __syncthreads();
    int pg = tid >> 2, quarter = tid & 3;
    int pb = c * 256 + pg * 4;
    v2f xp2[2][32];
    float xp[4];
    #pragma unroll
    for (int i = 0; i < 4; i++) {
        const float4* pp = (const float4*)(pts + (size_t)(pb + i) * 32);
        float e[32];
        #pragma unroll
        for (int t = 0; t < 8; t++) {
            float4 f = pp[t];
            xp2[i >> 1][4*t+0][i & 1] = f.x;
            xp2[i >> 1][4*t+1][i & 1] = f.y;
            xp2[i >> 1][4*t+2][i & 1] = f.z;
            xp2[i >> 1][4*t+3][i & 1] = f.w;
            e[4*t+0] = fmul(f.x, f.x);
            e[4*t+1] = fmul(f.y, f.y);
            e[4*t+2] = fmul(f.z, f.z);
            e[4*t+3] = fmul(f.w, f.w);
        }
        xp[i] = sum32_np(e);
    }
    float bd[4] = {3.4e38f, 3.4e38f, 3.4e38f, 3.4e38f};
    int bj[4] = {0x7fffffff, 0x7fffffff, 0x7fffffff, 0x7fffffff};
    for (int jj = 0; jj < 64; jj++) {
        int j = (jj << 2) | quarter;
        const float4* cj = (const float4*)(sc + j * 36);
        float w[32];
        #pragma unroll
        for (int t = 0; t < 8; t++) {
            float4 f = cj[t];
            w[4*t] = f.x; w[4*t+1] = f.y; w[4*t+2] = f.z; w[4*t+3] = f.w;
        }
        float sj = scc[j];
        v2f g0 = {0.f, 0.f}, g1 = {0.f, 0.f};
        #pragma unroll
        for (int t = 0; t < 32; t++) {
            v2f wv = {w[t], w[t]};
            g0 = __builtin_elementwise_fma(xp2[0][t], wv, g0);
            g1 = __builtin_elementwise_fma(xp2[1][t], wv, g1);
        }
        #pragma unroll
        for (int i = 0; i < 4; i++) {
            float g = (i < 2) ? g0[i & 1] : g1[i & 1];
            float d = fadd(fsub(xp[i], fmul(2.f, g)), sj);
            if (d < bd[i]) { bd[i] = d; bj[i] = j; }
        }
    }
    // lexicographic (d, j) combine across the 4 quarters
    #pragma unroll
    for (int i = 0; i < 4; i++) {
        float ob; int oj;
        ob = __shfl_xor(bd[i], 1); oj = __shfl_xor(bj[i], 1);
        if (ob < bd[i] || (ob == bd[i] && oj < bj[i])) { bd[i] = ob; bj[i] = oj; }
        ob = __shfl_xor(bd[i], 2); oj = __shfl_xor(bj[i], 2);
        if (ob < bd[i] || (ob == bd[i] && oj < bj[i])) { bd[i] = ob; bj[i] = oj; }
    }
    if (quarter == 0) {
        #pragma unroll
        for (int i = 0; i < 4; i++) {
            const float* cb = &sc[bj[i] * 36];
            float e[32];
            #pragma unroll
            for (int t = 0; t < 32; t++) {
                float xv = xp2[i >> 1][t][i & 1];
                e[t] = fabsf(fsub(cb[t], xv));
            }
            kd[pb + i] = sum32_np(e);
        }
    }
}

// ---------- top-256 via bit-descent select (exact stable set) -------
__global__ __launch_bounds__(256) void topk_v3(const float* __restrict__ kd,
        const float* __restrict__ k_t, const float* __restrict__ v_t,
        float* __restrict__ ksel, float* __restrict__ vsel) {
    __shared__ int wsum[4];
    __shared__ int sc1[256];
    __shared__ int out_src[256];
    int bh = blockIdx.x, tid = threadIdx.x;
    int wave = tid >> 6, lane = tid & 63;
    unsigned uv[16];
    {
        const unsigned* kdu = (const unsigned*)(kd + (size_t)bh * 4096);
        #pragma unroll
        for (int q = 0; q < 16; q++) uv[q] = kdu[tid * 16 + q];
    }
    unsigned T = 0u;
    for (int bit = 31; bit >= 0; bit--) {
        unsigned cand = T | (1u << bit);
        int c = 0;
        #pragma unroll
        for (int q = 0; q < 16; q++) c += (uv[q] >= cand) ? 1 : 0;
        c += __shfl_xor(c, 32); c += __shfl_xor(c, 16); c += __shfl_xor(c, 8);
        c += __shfl_xor(c, 4);  c += __shfl_xor(c, 2);  c += __shfl_xor(c, 1);
        if (lane == 0) wsum[wave] = c;
        __syncthreads();
        int tot = wsum[0] + wsum[1] + wsum[2] + wsum[3];
        __syncthreads();
        if (tot >= 256) T = cand;
    }
    int r;
    {
        int c = 0;
        #pragma unroll
        for (int q = 0; q < 16; q++) c += (uv[q] > T) ? 1 : 0;
        c += __shfl_xor(c, 32); c += __shfl_xor(c, 16); c += __shfl_xor(c, 8);
        c += __shfl_xor(c, 4);  c += __shfl_xor(c, 2);  c += __shfl_xor(c, 1);
        if (lane == 0) wsum[wave] = c;
        __syncthreads();
        r = 256 - (wsum[0] + wsum[1] + wsum[2] + wsum[3]);
        __syncthreads();
    }
    int ec = 0;
    #pragma unroll
    for (int q = 0; q < 16; q++) ec += (uv[q] == T) ? 1 : 0;
    sc1[tid] = ec;
    __syncthreads();
    for (int d = 1; d < 256; d <<= 1) {
        int t0 = sc1[tid];
        int u0 = (tid >= d) ? sc1[tid - d] : 0;
        __syncthreads();
        sc1[tid] = t0 + u0;
        __syncthreads();
    }
    int erank = (tid == 0) ? 0 : sc1[tid - 1];
    __syncthreads();
    bool incl[16];
    int ic = 0;
    #pragma unroll
    for (int q = 0; q < 16; q++) {
        unsigned u = uv[q];
        bool inc;
        if (u > T) inc = true;
        else if (u == T) { inc = (erank < r); erank++; }
        else inc = false;
        incl[q] = inc;
        ic += inc ? 1 : 0;
    }
    sc1[tid] = ic;
    __syncthreads();
    for (int d = 1; d < 256; d <<= 1) {
        int t0 = sc1[tid];
        int u0 = (tid >= d) ? sc1[tid - d] : 0;
        __syncthreads();
        sc1[tid] = t0 + u0;
        __syncthreads();
    }
    int pos = (tid == 0) ? 0 : sc1[tid - 1];
    int base_i = tid * 16;
    #pragma unroll
    for (int q = 0; q < 16; q++) {
        if (incl[q]) out_src[pos++] = base_i + q;
    }
    __syncthreads();
    for (int e = tid; e < 256 * 32; e += 256) {
        int jj = e >> 5, t = e & 31;
        int src = out_src[jj];
        ksel[(size_t)bh * 8192 + e] = k_t[((size_t)bh * 4096 + src) * 32 + t];
        vsel[(size_t)bh * 8192 + e] = v_t[((size_t)bh * 4096 + src) * 32 + t];
    }
}

// ---------- attention v4: 8-thread groups (4 slices x 2 dh), Q=4 ----
#define HP4 2052
__global__ __launch_bounds__(256, 2) void attn_v4(const float* __restrict__ q_t,
        const float* __restrict__ ksel, const float* __restrict__ vsel,
        float* __restrict__ out) {
    __shared__ float sk[4 * HP4];
    __shared__ float sv[4 * HP4];
    int bh = blockIdx.y, tid = threadIdx.x;
    {
        const float4* gk = (const float4*)(ksel + (size_t)bh * 8192);
        const float4* gv = (const float4*)(vsel + (size_t)bh * 8192);
        for (int i = tid; i < 2048; i += 256) {
            int s = i >> 9, idx = i & 511;
            ((float4*)(sk + s * HP4))[idx] = gk[i];
            ((float4*)(sv + s * HP4))[idx] = gv[i];
        }
    }
    __syncthreads();
    int grp = tid >> 3;              // 32 groups of 8 lanes
    int dh = tid & 1;                // dim half
    int slice = (tid >> 1) & 3;      // key quarter
    int p0 = bh * 4096 + blockIdx.x * 128 + grp * 4;
    float q[4][16];
    #pragma unroll
    for (int i = 0; i < 4; i++) {
        const float4* qp = (const float4*)(q_t + (size_t)(p0 + i) * 32 + dh * 16);
        #pragma unroll
        for (int t = 0; t < 4; t++) {
            float4 f = qp[t];
            q[i][4*t] = f.x; q[i][4*t+1] = f.y; q[i][4*t+2] = f.z; q[i][4*t+3] = f.w;
        }
    }
    float o[4][16];
    #pragma unroll
    for (int i = 0; i < 4; i++)
        #pragma unroll
        for (int t = 0; t < 16; t++) o[i][t] = 0.f;
    float ls[4] = {0.f, 0.f, 0.f, 0.f};
    const float* kb = sk + slice * HP4 + dh * 16;
    const float* vb = sv + slice * HP4 + dh * 16;
    for (int j = 0; j < 64; j++) {
        float kf[16];
        #pragma unroll
        for (int t = 0; t < 4; t++) {
            float4 f = *(const float4*)(kb + j * 32 + t * 4);
            kf[4*t] = f.x; kf[4*t+1] = f.y; kf[4*t+2] = f.z; kf[4*t+3] = f.w;
        }
        float ps[4];
        #pragma unroll
        for (int i = 0; i < 4; i++) {
            float a = 0.f, b2 = 0.f, c2 = 0.f, d2 = 0.f;
            #pragma unroll
            for (int t = 0; t < 4; t++) {
                a  += q[i][4*t]   * kf[4*t];
                b2 += q[i][4*t+1] * kf[4*t+1];
                c2 += q[i][4*t+2] * kf[4*t+2];
                d2 += q[i][4*t+3] * kf[4*t+3];
            }
            ps[i] = (a + b2) + (c2 + d2);
        }
        #pragma unroll
        for (int i = 0; i < 4; i++) ps[i] += __shfl_xor(ps[i], 1);  // dh combine
        float w[4];
        #pragma unroll
        for (int i = 0; i < 4; i++) {
            w[i] = __expf(ps[i] - 1.0f);
            ls[i] += w[i];
        }
        float vf[16];
        #pragma unroll
        for (int t = 0; t < 4; t++) {
            float4 f = *(const float4*)(vb + j * 32 + t * 4);
            vf[4*t] = f.x; vf[4*t+1] = f.y; vf[4*t+2] = f.z; vf[4*t+3] = f.w;
        }
        #pragma unroll
        for (int i = 0; i < 4; i++)
            #pragma unroll
            for (int t = 0; t < 16; t++) o[i][t] += w[i] * vf[t];
    }
    // combine the 4 key slices (tree: (s0+s1)+(s2+s3))
    #pragma unroll
    for (int i = 0; i < 4; i++) {
        #pragma unroll
        for (int t = 0; t < 16; t++) {
            o[i][t] += __shfl_xor(o[i][t], 2);
            o[i][t] += __shfl_xor(o[i][t], 4);
        }
        ls[i] += __shfl_xor(ls[i], 2);
        ls[i] += __shfl_xor(ls[i], 4);
    }
    if (slice == 0) {
        #pragma unroll
        for (int i = 0; i < 4; i++) {
            float inv = 1.f / ls[i];
            float4* op = (float4*)(out + (size_t)(p0 + i) * 32 + dh * 16);
            #pragma unroll
            for (int t = 0; t < 4; t++)
                op[t] = make_float4(o[i][4*t]*inv, o[i][4*t+1]*inv,
                                    o[i][4*t+2]*inv, o[i][4*t+3]*inv);
        }
    }
}

// ---------- unfold (bh,L,32) -> (b,256,L) ---------------------------
__global__ __launch_bounds__(256) void unfold_kernel(const float* __restrict__ att,
        float* __restrict__ Fo) {
    __shared__ float tbuf[32][65];
    int bh = blockIdx.y, l0 = blockIdx.x * 64;
    int b = bh >> 3, h = bh & 7;
    int tid = threadIdx.x;
    #pragma unroll
    for (int r = 0; r < 8; r++) {
        int e = r * 256 + tid;
        int l = e >> 5, d = e & 31;
        tbuf[d][l] = att[((size_t)bh * 4096 + l0 + l) * 32 + d];
    }
    __syncthreads();
    #pragma unroll
    for (int r = 0; r < 8; r++) {
        int e = r * 256 + tid;
        int d = e >> 6, l = e & 63;
        Fo[((size_t)b * 256 + h * 32 + d) * LSEQ + l0 + l] = tbuf[d][l];
    }
}

// ---------- final LN + scale + residual, LDS-cached (numpy orders) --
__global__ __launch_bounds__(64) void lnres_np(const float* __restrict__ x,
        const float* __restrict__ g, const float* __restrict__ bt,
        const float* __restrict__ gs, const float* __restrict__ qsrc,
        float* __restrict__ y) {
    __shared__ float xl[256 * 64];
    __shared__ float ql[256 * 64];
    int tid = threadIdx.x;
    int gid = blockIdx.x * 64 + tid;
    int b = gid >> 12, l = gid & 4095;
    const float* xb = x + (size_t)b * CDIM * LSEQ + l;
    const float* qb = qsrc + (size_t)b * CDIM * LSEQ + l;
    #pragma unroll 8
    for (int c = 0; c < 256; c++) {
        gld_lds4(xb + (size_t)c * LSEQ, xl + c * 64);
        gld_lds4(qb + (size_t)c * LSEQ, ql + c * 64);
    }
    __syncthreads();
    float s = 0.f;
    #pragma unroll 8
    for (int c = 0; c < 256; c++) s = fadd(s, xl[c * 64 + tid]);
    float mean = __fdiv_rn(s, 256.f);
    float s2 = 0.f;
    #pragma unroll 8
    for (int c = 0; c < 256; c++) {
        float d = fsub(xl[c * 64 + tid], mean);
        s2 = fadd(s2, fmul(d, d));
    }
    float var = __fdiv_rn(s2, 256.f);
    float den = fadd(__fsqrt_rn(var), 1e-6f);
    float scale = gs[0];
    float* yb = y + (size_t)b * CDIM * LSEQ + l;
    #pragma unroll 4
    for (int c = 0; c < 256; c++) {
        float d = fsub(xl[c * 64 + tid], mean);
        float r = fadd(__fdiv_rn(fmul(g[c], d), den), bt[c]);
        yb[(size_t)c * LSEQ] = fadd(fmul(scale, r), ql[c * 64 + tid]);
    }
}

// ==================================================================
extern "C" void kernel_launch(void* const* d_in, const int* in_sizes, int n_in,
                              void* d_out, int out_size, void* d_ws, size_t ws_size,
                              hipStream_t stream) {
    const float* qsrc   = (const float*)d_in[0];
    const float* ctx    = (const float*)d_in[1];
    const float* w_q    = (const float*)d_in[2];
    const float* w_kv   = (const float*)d_in[3];
    const float* w_out  = (const float*)d_in[4];
    const float* g_ctx  = (const float*)d_in[5];
    const float* b_ctx  = (const float*)d_in[6];
    const float* g_q    = (const float*)d_in[7];
    const float* b_q    = (const float*)d_in[8];
    const float* g_out  = (const float*)d_in[9];
    const float* b_out  = (const float*)d_in[10];
    const float* gs     = (const float*)d_in[11];

    char* base = (char*)d_ws;
    const size_t MB = 1024 * 1024;
    float* yln   = (float*)base;               // [0,8) ctx LN; later att
    float* att   = (float*)base;
    float* kvbuf = (float*)(base + 8 * MB);    // [8,24) kv conv; later y32
    float* y32   = (float*)(base + 8 * MB);
    float* qbuf  = (float*)(base + 24 * MB);   // [24,32) q conv; later Fo
    float* Fo    = (float*)(base + 24 * MB);
    float* q_t   = (float*)(base + 32 * MB);   // [32,40)
    float* k_t   = (float*)(base + 40 * MB);   // [40,48)
    float* v_t   = (float*)(base + 48 * MB);   // [48,56)
    char* SM = base + 56 * MB;
    float* xx_q      = (float*)(SM + 0);            // 256 KB
    float* cent      = (float*)(SM + 512 * 1024);   // 32 KB
    float* cc        = (float*)(SM + 576 * 1024);   // 1 KB
    int*   totals    = (int*)  (SM + 640 * 1024);   // 1 KB
    int*   asn       = (int*)  (SM + 704 * 1024);   // 256 KB
    int*   hist      = (int*)  (SM + 960 * 1024);   // 256 KB
    int*   chunkbase = (int*)  (SM + 1472 * 1024);  // 256 KB
    int*   perm      = (int*)  (SM + 1984 * 1024);  // 256 KB
    float* kd        = (float*)(SM + 2240 * 1024);  // 256 KB
    float* ksel      = (float*)(SM + 2496 * 1024);  // 512 KB
    float* vsel      = (float*)(SM + 3008 * 1024);  // 512 KB
    float* yln_q     = (float*)(base + 60 * MB);    // [60,68) q LN out

    ln2_np<<<256, 64, 0, stream>>>(ctx, g_ctx, b_ctx, yln,
                                   qsrc, g_q, b_q, yln_q);
    conv_all16<<<dim3(8, 48, 2), 256, 0, stream>>>(w_kv, yln, kvbuf,
                                                   w_q, yln_q, qbuf);
    fold3_np<<<768, 256, 0, stream>>>(kvbuf, qbuf, k_t, v_t, q_t, xx_q, cent, cc);

    for (int it = 0; it < 10; it++) {
        assign_full<<<256, 512, 0, stream>>>(q_t, xx_q, cent, cc, asn, hist);
        scan_chunks<<<256, 256, 0, stream>>>(hist, chunkbase, totals);
        scatter_v5<<<256, 256, 0, stream>>>(asn, chunkbase, totals, perm);
        sumk_v4<<<256, 256, 0, stream>>>(q_t, perm, totals, cent, cc);
    }

    kdist4p<<<256, 256, 0, stream>>>(k_t, cent, cc, kd);
    topk_v3<<<16, 256, 0, stream>>>(kd, k_t, v_t, ksel, vsel);
    attn_v4<<<dim3(32, 16), 256, 0, stream>>>(q_t, ksel, vsel, att);
    unfold_kernel<<<dim3(64, 16), 256, 0, stream>>>(att, Fo);
    conv_q8<false><<<dim3(4, 32, 2), 256, 0, stream>>>(w_out, Fo, y32);
    lnres_np<<<128, 64, 0, stream>>>(y32, g_out, b_out, gs, qsrc, (float*)d_out);
}